// Round 6
// baseline (314.144 us; speedup 1.0000x reference)
//
#include <hip/hip_runtime.h>
#include <math.h>

#define BB 16
#define LL 128
#define D_IN 8
#define HH 128
#define NLAYER 2
#define FUT 12
#define MDIM 2

typedef __attribute__((ext_vector_type(8))) __bf16 bf16x8;
typedef __attribute__((ext_vector_type(8))) short short8v;
typedef __attribute__((ext_vector_type(4))) float f32x4;

#define MFMA_B16(A, B, C) __builtin_amdgcn_mfma_f32_16x16x32_bf16(A, B, C, 0, 0, 0)

static __device__ __forceinline__ short f2bf(float f) {
    union { float f; unsigned u; } v; v.f = f;
    unsigned r = v.u + 0x7FFFu + ((v.u >> 16) & 1u);
    return (short)(r >> 16);
}

static __device__ __forceinline__ float tanh_fast(float x) {
    float e = __expf(2.f * x);
    return 1.f - 2.f / (e + 1.f);
}

// ---------------- fused: ts cumsum + h0 projection ----------------
__global__ __launch_bounds__(256) void k_init(const float* __restrict__ hist, const float* __restrict__ mask,
                                              const float* __restrict__ Wp, const float* __restrict__ bp,
                                              float* __restrict__ ts, float* __restrict__ h) {
    int b = blockIdx.x, tid = threadIdx.x;
    __shared__ float s[LL];
    if (tid < LL) s[tid] = fmaxf(hist[(b * LL + tid) * D_IN + 5], 0.f);
    __syncthreads();
    for (int d = 1; d < LL; d <<= 1) {
        float add = (tid < LL && tid >= d) ? s[tid - d] : 0.f;
        __syncthreads();
        if (tid < LL) s[tid] += add;
        __syncthreads();
    }
    if (tid < LL) ts[b * LL + tid] = s[tid];
    int k = tid & (HH - 1);
    float wp_r[D_IN];
#pragma unroll
    for (int f = 0; f < D_IN; f++) wp_r[f] = Wp[f * HH + k];
    float bpk = bp[k];
    int jbase = tid >> 7;
    for (int e = 0; e < 64; e++) {
        int j = e * 2 + jbase;
        int bj = b * LL + j;
        const float* hr = hist + (size_t)bj * D_IN;
        float acc = bpk;
#pragma unroll
        for (int f = 0; f < D_IN; f++) acc += hr[f] * wp_r[f];
        h[(size_t)bj * HH + k] = acc * (mask[bj] > 0.f ? 1.f : 0.f);
    }
}

// ---------------- fused: composed matrices (Amat/Mmat/ca/cm) + weight transpose-cast ----------------
__global__ __launch_bounds__(HH) void k_setup(const float* __restrict__ We2, const float* __restrict__ be2,
                                              const float* __restrict__ Wa1, const float* __restrict__ ba1,
                                              const float* __restrict__ Wm1, const float* __restrict__ bm1,
                                              const float* __restrict__ Wo1, const float* __restrict__ Wm2,
                                              const float* __restrict__ Wo2,
                                              short* __restrict__ AmT, short* __restrict__ MmT,
                                              float* __restrict__ ca, float* __restrict__ cm,
                                              short* __restrict__ WT4, short* __restrict__ WT3) {
    __shared__ float row[HH];
    int blk = blockIdx.x, q = threadIdx.x;
    const int NC = NLAYER * (HH + 1);
    if (blk < NC) {
        int l = blk / (HH + 1);
        int p = blk % (HH + 1);
        const float* WaE = Wa1 + (size_t)(l * 3 * HH + 2 * HH) * HH;
        const float* WmE = Wm1 + (size_t)(l * 2 * HH + HH) * HH;
        if (p < HH) {
            row[q] = We2[(size_t)(l * HH + p) * HH + q];
            __syncthreads();
            float a = 0.f, m = 0.f;
            for (int k = 0; k < HH; k++) { float w = row[k]; a += w * WaE[k * HH + q]; m += w * WmE[k * HH + q]; }
            AmT[(size_t)l * HH * HH + q * HH + p] = f2bf(a);
            MmT[(size_t)l * HH * HH + q * HH + p] = f2bf(m);
        } else {
            row[q] = be2[l * HH + q];
            __syncthreads();
            float a = 0.f, m = 0.f;
            for (int k = 0; k < HH; k++) { float w = row[k]; a += w * WaE[k * HH + q]; m += w * WmE[k * HH + q]; }
            ca[l * HH + q] = a + ba1[l * HH + q];
            cm[l * HH + q] = m + bm1[l * HH + q];
        }
    } else {
        int m7 = blk - NC;
        int l = m7 / 7, m = m7 % 7;
        const float* src;
        switch (m) {
            case 0: src = Wa1 + (size_t)(l * 3 * HH) * HH; break;
            case 1: src = Wa1 + (size_t)(l * 3 * HH + HH) * HH; break;
            case 2: src = Wm1 + (size_t)(l * 2 * HH) * HH; break;
            case 3: src = Wo1 + (size_t)(l * 2 * HH) * HH; break;
            case 4: src = Wm2 + (size_t)l * HH * HH; break;
            case 5: src = Wo1 + (size_t)(l * 2 * HH + HH) * HH; break;
            default: src = Wo2 + (size_t)l * HH * HH; break;
        }
        short* dst = (m < 4) ? (WT4 + (size_t)(l * 4 + m) * HH * HH)
                             : (WT3 + (size_t)(l * 3 + (m - 4)) * HH * HH);
#pragma unroll 4
        for (int e = 0; e < 128; e++) {
            int idx = e * 128 + q;
            int c = idx >> 7, kk = idx & (HH - 1);
            dst[c * HH + kk] = f2bf(src[kk * HH + c]);
        }
    }
}

// ---------------- batched pre-projections via MFMA: base_a, da, base_m, oa (layer 0 only) ----------------
__global__ __launch_bounds__(256) void k_pre(const float* __restrict__ h, const short* __restrict__ WT4,
                                             const float* __restrict__ ca, const float* __restrict__ cm,
                                             float* __restrict__ base_a, float* __restrict__ da,
                                             float* __restrict__ base_m, float* __restrict__ oa, int l) {
    __shared__ __align__(16) short hA[32][136];
    const int tid = threadIdx.x, lane = tid & 63, wv = tid >> 6;
    const int lo = lane & 15, g4 = lane >> 4;
    const int r0 = blockIdx.x * 32;
    {
        int row = tid >> 3, cc = (tid & 7) * 16;
        const float* hr = h + (size_t)(r0 + row) * HH + cc;
        short8v pk;
#pragma unroll
        for (int e = 0; e < 8; e++) pk[e] = f2bf(hr[e]);
        *(short8v*)&hA[row][cc] = pk;
#pragma unroll
        for (int e = 0; e < 8; e++) pk[e] = f2bf(hr[8 + e]);
        *(short8v*)&hA[row][cc + 8] = pk;
    }
    __syncthreads();
    bf16x8 af[2][4];
#pragma unroll
    for (int mt = 0; mt < 2; mt++)
#pragma unroll
        for (int ks = 0; ks < 4; ks++)
            af[mt][ks] = *(const bf16x8*)&hA[mt * 16 + lo][ks * 32 + g4 * 8];
    const short* Wl = WT4 + (size_t)(l * 4 + wv) * HH * HH;
    float* dst;
    const float* bias = nullptr;
    if (wv == 0) { dst = base_a; bias = ca + l * HH; }
    else if (wv == 1) dst = da;
    else if (wv == 2) { dst = base_m; bias = cm + l * HH; }
    else dst = oa;
#pragma unroll
    for (int ct = 0; ct < 8; ct++) {
        int col = ct * 16 + lo;
        bf16x8 Bf[4];
#pragma unroll
        for (int ks = 0; ks < 4; ks++)
            Bf[ks] = *(const bf16x8*)(Wl + (size_t)col * HH + ks * 32 + g4 * 8);
        f32x4 acc[2];
        acc[0] = (f32x4){0.f, 0.f, 0.f, 0.f};
        acc[1] = (f32x4){0.f, 0.f, 0.f, 0.f};
#pragma unroll
        for (int ks = 0; ks < 4; ks++) {
            acc[0] = MFMA_B16(af[0][ks], Bf[ks], acc[0]);
            acc[1] = MFMA_B16(af[1][ks], Bf[ks], acc[1]);
        }
        float bv = bias ? bias[col] : 0.f;
#pragma unroll
        for (int mt = 0; mt < 2; mt++)
#pragma unroll
            for (int rg = 0; rg < 4; rg++)
                dst[(size_t)(r0 + mt * 16 + g4 * 4 + rg) * HH + col] = acc[mt][rg] + bv;
    }
}

// ---------------- attention core: 512 threads, one block per (b,i), wave owns 16 cols ----------------
__global__ __launch_bounds__(512) void k_attn(
    const float* __restrict__ hist, const float* __restrict__ mask, const float* __restrict__ ts,
    const float* __restrict__ base_a_g, const float* __restrict__ base_m_g, const float* __restrict__ da,
    const short* __restrict__ AmT, const short* __restrict__ MmT,
    const float* __restrict__ wa2, const float* __restrict__ ba2,
    const float* __restrict__ We1, const float* __restrict__ be1,
    float* __restrict__ v_out, int l) {
    __shared__ __align__(16) short t_lds[LL][136];   // 34816 B
    __shared__ float bufA[1024];                     // We1[0..511], be1[512..639] -> att8 [8][128]
    __shared__ float val_s[128], base_a[128], base_m[128], wa2_s[128];  // 2048 B  (total 40960)

    const int tid = threadIdx.x;
    const int lane = tid & 63;
    const int wv = tid >> 6;            // 0..7: wave owns cols [wv*16, wv*16+16)
    const int lo = lane & 15, g4 = lane >> 4;
    const int k0 = wv * 16 + lo;
    const int bi = blockIdx.x, b = bi >> 7, i = bi & (LL - 1);

    // --- B1 fragments (Amat^T bf16), issue early (L2) ---
    bf16x8 Bf[4];
#pragma unroll
    for (int ks = 0; ks < 4; ks++)
        Bf[ks] = *(const bf16x8*)(AmT + (size_t)l * HH * HH + (size_t)k0 * HH + ks * 32 + g4 * 8);

    // --- stage ---
    bufA[tid] = We1[l * 4 * HH + tid];
    if (tid < LL) {
        val_s[tid] = mask[b * LL + tid];
        wa2_s[tid] = wa2[l * HH + tid];
        bufA[512 + tid] = be1[l * HH + tid];
        base_a[tid] = base_a_g[(size_t)bi * HH + tid];
        base_m[tid] = base_m_g[(size_t)bi * HH + tid];
    }
    __syncthreads();

    // --- per-thread edge features + t = relu(ef @ We1 + be1) -> LDS bf16 ---
    {
        int jj = tid & (LL - 1);
        int q4 = tid >> 7;  // 0..3
        const float* hri = hist + (size_t)(b * LL + i) * D_IN;
        const float* hrj = hist + (size_t)(b * LL + jj) * D_IN;
        float dlat = hri[0] - hrj[0], dlon = hri[1] - hrj[1];
        float ea = sqrtf(dlat * dlat + dlon * dlon + 1e-8f);
        float eb = fabsf(ts[b * LL + i] - ts[b * LL + jj]) * (1.f / 300.f);
        float ec = (hri[6] == hrj[6]) ? 1.f : 0.f;
        float ed = (jj == i) ? 1.f : 0.f;
#pragma unroll
        for (int pass = 0; pass < 4; pass++) {
            int r0 = (q4 + pass * 4) * 8;
            short8v pk;
#pragma unroll
            for (int e = 0; e < 8; e++) {
                int r = r0 + e;
                float v = ea * bufA[r] + eb * bufA[128 + r] + ec * bufA[256 + r] + ed * bufA[384 + r] + bufA[512 + r];
                pk[e] = f2bf(fmaxf(v, 0.f));
            }
            *(short8v*)&t_lds[jj][r0] = pk;
        }
    }

    // --- acc init from da (loads hide under t-compute) ---
    f32x4 acc[8];
    const float* da_b = da + (size_t)(b * LL) * HH;
#pragma unroll
    for (int jt = 0; jt < 8; jt++)
#pragma unroll
        for (int rg = 0; rg < 4; rg++)
            acc[jt][rg] = da_b[(size_t)(jt * 16 + g4 * 4 + rg) * HH + k0];
    __syncthreads();

    // --- GEMM1: U_a = t @ Amat (this wave's 16 cols) ---
#pragma unroll
    for (int ks = 0; ks < 4; ks++) {
#pragma unroll
        for (int jh = 0; jh < 2; jh++) {
            bf16x8 tf[4];
#pragma unroll
            for (int m = 0; m < 4; m++)
                tf[m] = *(const bf16x8*)&t_lds[(jh * 4 + m) * 16 + lo][ks * 32 + g4 * 8];
#pragma unroll
            for (int m = 0; m < 4; m++)
                acc[jh * 4 + m] = MFMA_B16(tf[m], Bf[ks], acc[jh * 4 + m]);
        }
    }

    // --- preload B2 (Mmat^T) ---
#pragma unroll
    for (int ks = 0; ks < 4; ks++)
        Bf[ks] = *(const bf16x8*)(MmT + (size_t)l * HH * HH + (size_t)k0 * HH + ks * 32 + g4 * 8);

    // --- tanh + att partials (sum over this wave's 16 cols) -> bufA[wv*128 + j] ---
    {
        float ba0 = base_a[k0];
        float w0a = wa2_s[k0];
#pragma unroll
        for (int jt = 0; jt < 8; jt++) {
#pragma unroll
            for (int rg = 0; rg < 4; rg++) {
                float p = tanh_fast(acc[jt][rg] + ba0) * w0a;
                p += __shfl_xor(p, 1);
                p += __shfl_xor(p, 2);
                p += __shfl_xor(p, 4);
                p += __shfl_xor(p, 8);
                if (lo == 0) bufA[wv * LL + jt * 16 + g4 * 4 + rg] = p;
            }
        }
    }
    __syncthreads();

    // --- redundant per-wave softmax (each lane handles j=lane, j=lane+64) ---
    float w0, w1;
    {
        const float inv = 0.08838834764831845f;  // 1/sqrt(128)
        float ba2l = ba2[l];
        float vi = val_s[i];
        float a0 = ba2l, a1 = ba2l;
#pragma unroll
        for (int w = 0; w < 8; w++) {
            a0 += bufA[w * LL + lane];
            a1 += bufA[w * LL + 64 + lane];
        }
        a0 *= inv; a1 *= inv;
        if (!(val_s[lane] > 0.f) || !(vi > 0.f)) a0 = -1e9f;
        if (!(val_s[64 + lane] > 0.f) || !(vi > 0.f)) a1 = -1e9f;
        float m = fmaxf(a0, a1);
#pragma unroll
        for (int d = 1; d < 64; d <<= 1) m = fmaxf(m, __shfl_xor(m, d));
        float e0 = __expf(a0 - m), e1 = __expf(a1 - m);
        float s = e0 + e1;
#pragma unroll
        for (int d = 1; d < 64; d <<= 1) s += __shfl_xor(s, d);
        float rs = 1.f / s;
        w0 = e0 * rs;
        w1 = e1 * rs;
    }

    // --- GEMM2: U_m = t @ Mmat ---
#pragma unroll
    for (int jt = 0; jt < 8; jt++)
#pragma unroll
        for (int rg = 0; rg < 4; rg++) acc[jt][rg] = 0.f;
#pragma unroll
    for (int ks = 0; ks < 4; ks++) {
#pragma unroll
        for (int jh = 0; jh < 2; jh++) {
            bf16x8 tf[4];
#pragma unroll
            for (int m = 0; m < 4; m++)
                tf[m] = *(const bf16x8*)&t_lds[(jh * 4 + m) * 16 + lo][ks * 32 + g4 * 8];
#pragma unroll
            for (int m = 0; m < 4; m++)
                acc[jh * 4 + m] = MFMA_B16(tf[m], Bf[ks], acc[jh * 4 + m]);
        }
    }

    // --- weighted relu-msg sum over j; write v directly ---
    {
        float bm0 = base_m[k0];
        float mac = 0.f;
#pragma unroll
        for (int jt = 0; jt < 8; jt++) {
#pragma unroll
            for (int rg = 0; rg < 4; rg++) {
                int j = jt * 16 + g4 * 4 + rg;
                float wj = (jt < 4) ? __shfl(w0, j) : __shfl(w1, j - 64);
                mac += wj * fmaxf(acc[jt][rg] + bm0, 0.f);
            }
        }
        mac += __shfl_xor(mac, 16);
        mac += __shfl_xor(mac, 32);
        if (g4 == 0) v_out[(size_t)bi * HH + k0] = mac;
    }
}

// ---------------- batched post: agg -> x1 -> y, LayerNorm; optionally fused next-layer pre ----------------
__global__ __launch_bounds__(256) void k_post(
    const float* __restrict__ v, const float* __restrict__ oa_in, const float* __restrict__ h,
    const float* __restrict__ mask, const short* __restrict__ WT3,
    const float* __restrict__ bm2, const float* __restrict__ bo1, const float* __restrict__ bo2,
    const float* __restrict__ ln_g, const float* __restrict__ ln_b,
    float* __restrict__ hout, float* __restrict__ hcopy, int l,
    int do_pre, const short* __restrict__ WT4, const float* __restrict__ ca, const float* __restrict__ cm,
    float* __restrict__ base_a, float* __restrict__ da, float* __restrict__ base_m, float* __restrict__ oa_out) {
    __shared__ __align__(16) short xA[32][136];
    __shared__ __align__(16) short iA[32][136];
    __shared__ float red[2][4][32];
    const int tid = threadIdx.x, lane = tid & 63, wv = tid >> 6;
    const int lo = lane & 15, g4 = lane >> 4;
    const int r0 = blockIdx.x * 32;

    float oaR[2][2][4], hR[2][2][4], vmR[2][4];
    float bm2R[2], bo1R[2], bo2R[2], gR[2], bR[2];
#pragma unroll
    for (int ct = 0; ct < 2; ct++) {
        int c = wv * 32 + ct * 16 + lo;
        bm2R[ct] = bm2[l * HH + c];
        bo1R[ct] = bo1[l * HH + c];
        bo2R[ct] = bo2[l * HH + c];
        gR[ct] = ln_g[l * HH + c];
        bR[ct] = ln_b[l * HH + c];
    }
#pragma unroll
    for (int mt = 0; mt < 2; mt++)
#pragma unroll
        for (int rg = 0; rg < 4; rg++) {
            int r = r0 + mt * 16 + g4 * 4 + rg;
            vmR[mt][rg] = mask[r];
#pragma unroll
            for (int ct = 0; ct < 2; ct++) {
                int c = wv * 32 + ct * 16 + lo;
                oaR[mt][ct][rg] = oa_in[(size_t)r * HH + c];
                hR[mt][ct][rg] = h[(size_t)r * HH + c];
            }
        }

    {
        int row = tid >> 3, cc = (tid & 7) * 16;
        const float* vr = v + (size_t)(r0 + row) * HH + cc;
        short8v pk;
#pragma unroll
        for (int e = 0; e < 8; e++) pk[e] = f2bf(vr[e]);
        *(short8v*)&xA[row][cc] = pk;
#pragma unroll
        for (int e = 0; e < 8; e++) pk[e] = f2bf(vr[8 + e]);
        *(short8v*)&xA[row][cc + 8] = pk;
    }
    __syncthreads();

    bf16x8 af[2][4], Bf[2][4];
    f32x4 acc[2][2];

    // ---- GEMM A: agg = v @ Wm2^T + bm2 -> iA ----
    {
        const short* W = WT3 + (size_t)(l * 3 + 0) * HH * HH;
#pragma unroll
        for (int mt = 0; mt < 2; mt++)
#pragma unroll
            for (int ks = 0; ks < 4; ks++)
                af[mt][ks] = *(const bf16x8*)&xA[mt * 16 + lo][ks * 32 + g4 * 8];
#pragma unroll
        for (int ct = 0; ct < 2; ct++) {
            int col = wv * 32 + ct * 16 + lo;
#pragma unroll
            for (int ks = 0; ks < 4; ks++)
                Bf[ct][ks] = *(const bf16x8*)(W + (size_t)col * HH + ks * 32 + g4 * 8);
        }
#pragma unroll
        for (int mt = 0; mt < 2; mt++)
#pragma unroll
            for (int ct = 0; ct < 2; ct++) acc[mt][ct] = (f32x4){0.f, 0.f, 0.f, 0.f};
#pragma unroll
        for (int ks = 0; ks < 4; ks++)
#pragma unroll
            for (int mt = 0; mt < 2; mt++) {
                acc[mt][0] = MFMA_B16(af[mt][ks], Bf[0][ks], acc[mt][0]);
                acc[mt][1] = MFMA_B16(af[mt][ks], Bf[1][ks], acc[mt][1]);
            }
#pragma unroll
        for (int mt = 0; mt < 2; mt++)
#pragma unroll
            for (int ct = 0; ct < 2; ct++)
#pragma unroll
                for (int rg = 0; rg < 4; rg++)
                    iA[mt * 16 + g4 * 4 + rg][wv * 32 + ct * 16 + lo] = f2bf(acc[mt][ct][rg] + bm2R[ct]);
    }
    __syncthreads();

    // ---- GEMM B: x1 = relu(agg @ Wo1H^T + oa + bo1) -> xA ----
    {
        const short* W = WT3 + (size_t)(l * 3 + 1) * HH * HH;
#pragma unroll
        for (int mt = 0; mt < 2; mt++)
#pragma unroll
            for (int ks = 0; ks < 4; ks++)
                af[mt][ks] = *(const bf16x8*)&iA[mt * 16 + lo][ks * 32 + g4 * 8];
#pragma unroll
        for (int ct = 0; ct < 2; ct++) {
            int col = wv * 32 + ct * 16 + lo;
#pragma unroll
            for (int ks = 0; ks < 4; ks++)
                Bf[ct][ks] = *(const bf16x8*)(W + (size_t)col * HH + ks * 32 + g4 * 8);
        }
#pragma unroll
        for (int mt = 0; mt < 2; mt++)
#pragma unroll
            for (int ct = 0; ct < 2; ct++) acc[mt][ct] = (f32x4){0.f, 0.f, 0.f, 0.f};
#pragma unroll
        for (int ks = 0; ks < 4; ks++)
#pragma unroll
            for (int mt = 0; mt < 2; mt++) {
                acc[mt][0] = MFMA_B16(af[mt][ks], Bf[0][ks], acc[mt][0]);
                acc[mt][1] = MFMA_B16(af[mt][ks], Bf[1][ks], acc[mt][1]);
            }
        __syncthreads();
#pragma unroll
        for (int mt = 0; mt < 2; mt++)
#pragma unroll
            for (int ct = 0; ct < 2; ct++)
#pragma unroll
                for (int rg = 0; rg < 4; rg++)
                    xA[mt * 16 + g4 * 4 + rg][wv * 32 + ct * 16 + lo] =
                        f2bf(fmaxf(acc[mt][ct][rg] + oaR[mt][ct][rg] + bo1R[ct], 0.f));
    }
    __syncthreads();

    // ---- GEMM C: y = x1 @ Wo2^T + bo2 + h; LayerNorm ----
    float y[2][2][4];
    {
        const short* W = WT3 + (size_t)(l * 3 + 2) * HH * HH;
#pragma unroll
        for (int mt = 0; mt < 2; mt++)
#pragma unroll
            for (int ks = 0; ks < 4; ks++)
                af[mt][ks] = *(const bf16x8*)&xA[mt * 16 + lo][ks * 32 + g4 * 8];
#pragma unroll
        for (int ct = 0; ct < 2; ct++) {
            int col = wv * 32 + ct * 16 + lo;
#pragma unroll
            for (int ks = 0; ks < 4; ks++)
                Bf[ct][ks] = *(const bf16x8*)(W + (size_t)col * HH + ks * 32 + g4 * 8);
        }
#pragma unroll
        for (int mt = 0; mt < 2; mt++)
#pragma unroll
            for (int ct = 0; ct < 2; ct++) acc[mt][ct] = (f32x4){0.f, 0.f, 0.f, 0.f};
#pragma unroll
        for (int ks = 0; ks < 4; ks++)
#pragma unroll
            for (int mt = 0; mt < 2; mt++) {
                acc[mt][0] = MFMA_B16(af[mt][ks], Bf[0][ks], acc[mt][0]);
                acc[mt][1] = MFMA_B16(af[mt][ks], Bf[1][ks], acc[mt][1]);
            }
#pragma unroll
        for (int mt = 0; mt < 2; mt++)
#pragma unroll
            for (int ct = 0; ct < 2; ct++)
#pragma unroll
                for (int rg = 0; rg < 4; rg++)
                    y[mt][ct][rg] = acc[mt][ct][rg] + bo2R[ct] + hR[mt][ct][rg];
    }
#pragma unroll
    for (int mt = 0; mt < 2; mt++)
#pragma unroll
        for (int rg = 0; rg < 4; rg++) {
            float s = y[mt][0][rg] + y[mt][1][rg];
            float s2 = y[mt][0][rg] * y[mt][0][rg] + y[mt][1][rg] * y[mt][1][rg];
#pragma unroll
            for (int d = 1; d < 16; d <<= 1) { s += __shfl_xor(s, d); s2 += __shfl_xor(s2, d); }
            if (lo == 0) {
                red[0][wv][mt * 16 + g4 * 4 + rg] = s;
                red[1][wv][mt * 16 + g4 * 4 + rg] = s2;
            }
        }
    __syncthreads();
#pragma unroll
    for (int mt = 0; mt < 2; mt++)
#pragma unroll
        for (int rg = 0; rg < 4; rg++) {
            int rl = mt * 16 + g4 * 4 + rg;
            float mu = (red[0][0][rl] + red[0][1][rl] + red[0][2][rl] + red[0][3][rl]) * (1.f / HH);
            float ex2 = (red[1][0][rl] + red[1][1][rl] + red[1][2][rl] + red[1][3][rl]) * (1.f / HH);
            float var = ex2 - mu * mu;
            float rs = rsqrtf(var + 1e-5f);
            float vm = vmR[mt][rg] > 0.f ? 1.f : 0.f;
            int r = r0 + rl;
#pragma unroll
            for (int ct = 0; ct < 2; ct++) {
                int c = wv * 32 + ct * 16 + lo;
                float hv = ((y[mt][ct][rg] - mu) * rs * gR[ct] + bR[ct]) * vm;
                hout[(size_t)r * HH + c] = hv;
                if (hcopy) hcopy[(size_t)r * HH + c] = hv;
                if (do_pre) xA[rl][c] = f2bf(hv);
            }
        }

    if (do_pre) {
        __syncthreads();
        bf16x8 af2[2][4];
#pragma unroll
        for (int mt = 0; mt < 2; mt++)
#pragma unroll
            for (int ks = 0; ks < 4; ks++)
                af2[mt][ks] = *(const bf16x8*)&xA[mt * 16 + lo][ks * 32 + g4 * 8];
        int ln = l + 1;
        const short* Wl = WT4 + (size_t)(ln * 4 + wv) * HH * HH;
        float* dst;
        const float* bias = nullptr;
        if (wv == 0) { dst = base_a; bias = ca + ln * HH; }
        else if (wv == 1) dst = da;
        else if (wv == 2) { dst = base_m; bias = cm + ln * HH; }
        else dst = oa_out;
#pragma unroll
        for (int ct = 0; ct < 8; ct++) {
            int col = ct * 16 + lo;
            bf16x8 Bf2[4];
#pragma unroll
            for (int ks = 0; ks < 4; ks++)
                Bf2[ks] = *(const bf16x8*)(Wl + (size_t)col * HH + ks * 32 + g4 * 8);
            f32x4 a2[2];
            a2[0] = (f32x4){0.f, 0.f, 0.f, 0.f};
            a2[1] = (f32x4){0.f, 0.f, 0.f, 0.f};
#pragma unroll
            for (int ks = 0; ks < 4; ks++) {
                a2[0] = MFMA_B16(af2[0][ks], Bf2[ks], a2[0]);
                a2[1] = MFMA_B16(af2[1][ks], Bf2[ks], a2[1]);
            }
            float bv = bias ? bias[col] : 0.f;
#pragma unroll
            for (int mt = 0; mt < 2; mt++)
#pragma unroll
                for (int rg = 0; rg < 4; rg++)
                    dst[(size_t)(r0 + mt * 16 + g4 * 4 + rg) * HH + col] = a2[mt][rg] + bv;
        }
    }
}

// ---------------- decoder ----------------
__global__ __launch_bounds__(HH) void k_dec(const float* __restrict__ hist, const float* __restrict__ mask,
                                            const float* __restrict__ h, const float* __restrict__ hg,
                                            const float* __restrict__ hb, const float* __restrict__ Wh1,
                                            const float* __restrict__ bh1, const float* __restrict__ Wh2,
                                            const float* __restrict__ bh2, float* __restrict__ out) {
    int b = blockIdx.x, t = threadIdx.x;
    const int N = D_IN + HH;  // 136
    __shared__ float red[HH], x_s[D_IN + HH], u_s[HH];
    red[t] = mask[b * LL + t];
    __syncthreads();
    for (int s = 64; s > 0; s >>= 1) { if (t < s) red[t] += red[t + s]; __syncthreads(); }
    int vc = (int)red[0];
    vc = min(max(vc, 1), LL);
    int last = vc - 1;
    __syncthreads();
    if (t < D_IN) x_s[t] = hist[(size_t)(b * LL + last) * D_IN + t];
    x_s[D_IN + t] = h[(size_t)(b * LL + last) * HH + t];
    __syncthreads();
    float ps = 0.f;
    for (int f = t; f < N; f += HH) ps += x_s[f];
    red[t] = ps;
    __syncthreads();
    for (int s = 64; s > 0; s >>= 1) { if (t < s) red[t] += red[t + s]; __syncthreads(); }
    float mu = red[0] / N;
    __syncthreads();
    ps = 0.f;
    for (int f = t; f < N; f += HH) { float d = x_s[f] - mu; ps += d * d; }
    red[t] = ps;
    __syncthreads();
    for (int s = 64; s > 0; s >>= 1) { if (t < s) red[t] += red[t + s]; __syncthreads(); }
    float var = red[0] / N;
    float rs = rsqrtf(var + 1e-5f);
    __syncthreads();
    for (int f = t; f < N; f += HH) x_s[f] = (x_s[f] - mu) * rs * hg[f] + hb[f];
    __syncthreads();
    float acc = bh1[t];
    for (int f = 0; f < N; f++) acc += x_s[f] * Wh1[f * HH + t];
    u_s[t] = fmaxf(acc, 0.f);
    __syncthreads();
    if (t < FUT * MDIM) {
        float o = bh2[t];
        for (int k = 0; k < HH; k++) o += u_s[k] * Wh2[k * FUT * MDIM + t];
        if (isnan(o)) o = 0.f;
        else if (isinf(o)) o = (o > 0.f) ? 1e4f : -1e4f;
        out[b * FUT * MDIM + t] = o;
    }
}

extern "C" void kernel_launch(void* const* d_in, const int* in_sizes, int n_in,
                              void* d_out, int out_size, void* d_ws, size_t ws_size,
                              hipStream_t stream) {
    const float* hist = (const float*)d_in[0];
    const float* mask = (const float*)d_in[1];
    const float* Wp  = (const float*)d_in[2];
    const float* bp  = (const float*)d_in[3];
    const float* We1 = (const float*)d_in[4];
    const float* be1 = (const float*)d_in[5];
    const float* We2 = (const float*)d_in[6];
    const float* be2 = (const float*)d_in[7];
    const float* Wa1 = (const float*)d_in[8];
    const float* ba1 = (const float*)d_in[9];
    const float* wa2 = (const float*)d_in[10];
    const float* ba2 = (const float*)d_in[11];
    const float* Wm1 = (const float*)d_in[12];
    const float* bm1 = (const float*)d_in[13];
    const float* Wm2 = (const float*)d_in[14];
    const float* bm2 = (const float*)d_in[15];
    const float* Wo1 = (const float*)d_in[16];
    const float* bo1 = (const float*)d_in[17];
    const float* Wo2 = (const float*)d_in[18];
    const float* bo2 = (const float*)d_in[19];
    const float* ln_g = (const float*)d_in[20];
    const float* ln_b = (const float*)d_in[21];
    const float* hg  = (const float*)d_in[22];
    const float* hb  = (const float*)d_in[23];
    const float* Wh1 = (const float*)d_in[24];
    const float* bh1 = (const float*)d_in[25];
    const float* Wh2 = (const float*)d_in[26];
    const float* bh2 = (const float*)d_in[27];
    float* out = (float*)d_out;

    float* ws = (float*)d_ws;
    float* ts_w   = ws; ws += BB * LL;
    float* h_w    = ws; ws += BB * LL * HH;
    float* da_w   = ws; ws += BB * LL * HH;
    float* ba_w   = ws; ws += BB * LL * HH;   // base_a
    float* bm_w   = ws; ws += BB * LL * HH;   // base_m
    float* oa_w   = ws; ws += BB * LL * HH;
    float* v_w    = ws; ws += BB * LL * HH;
    float* ca_w   = ws; ws += NLAYER * HH;
    float* cm_w   = ws; ws += NLAYER * HH;
    short* AmT_w  = (short*)ws; ws += NLAYER * HH * HH / 2;
    short* MmT_w  = (short*)ws; ws += NLAYER * HH * HH / 2;
    short* WT4_w  = (short*)ws; ws += NLAYER * 4 * HH * HH / 2;
    short* WT3_w  = (short*)ws; ws += NLAYER * 3 * HH * HH / 2;

    k_init<<<BB, 256, 0, stream>>>(hist, mask, Wp, bp, ts_w, h_w);
    k_setup<<<NLAYER * (HH + 1) + NLAYER * 7, HH, 0, stream>>>(We2, be2, Wa1, ba1, Wm1, bm1,
                                                               Wo1, Wm2, Wo2, AmT_w, MmT_w, ca_w, cm_w,
                                                               WT4_w, WT3_w);
    k_pre<<<BB * LL / 32, 256, 0, stream>>>(h_w, WT4_w, ca_w, cm_w, ba_w, da_w, bm_w, oa_w, 0);
    for (int l = 0; l < NLAYER; l++) {
        k_attn<<<BB * LL, 512, 0, stream>>>(hist, mask, ts_w, ba_w, bm_w, da_w, AmT_w, MmT_w,
                                            wa2, ba2, We1, be1, v_w, l);
        int do_pre = (l < NLAYER - 1) ? 1 : 0;
        float* hcopy = (l == NLAYER - 1) ? (out + BB * FUT * MDIM) : nullptr;
        k_post<<<BB * LL / 32, 256, 0, stream>>>(v_w, oa_w, h_w, mask, WT3_w, bm2, bo1, bo2,
                                                 ln_g, ln_b, h_w, hcopy, l,
                                                 do_pre, WT4_w, ca_w, cm_w, ba_w, da_w, bm_w, oa_w);
    }
    k_dec<<<BB, HH, 0, stream>>>(hist, mask, h_w, hg, hb, Wh1, bh1, Wh2, bh2, out);
}

// Round 7
// 283.693 us; speedup vs baseline: 1.1073x; 1.1073x over previous
//
#include <hip/hip_runtime.h>
#include <math.h>

#define BB 16
#define LL 128
#define D_IN 8
#define HH 128
#define NLAYER 2
#define FUT 12
#define MDIM 2

typedef __attribute__((ext_vector_type(8))) __bf16 bf16x8;
typedef __attribute__((ext_vector_type(8))) short short8v;
typedef __attribute__((ext_vector_type(4))) float f32x4;

#define MFMA_B16(A, B, C) __builtin_amdgcn_mfma_f32_16x16x32_bf16(A, B, C, 0, 0, 0)

static __device__ __forceinline__ short f2bf(float f) {
    union { float f; unsigned u; } v; v.f = f;
    unsigned r = v.u + 0x7FFFu + ((v.u >> 16) & 1u);
    return (short)(r >> 16);
}

static __device__ __forceinline__ float tanh_fast(float x) {
    float e = __expf(2.f * x);
    return 1.f - 2.f / (e + 1.f);
}

// ---------------- merged prep: ts+h0 (blocks 0..15) | compose (16..273) | transpose (274..287) ----------------
__global__ __launch_bounds__(256) void k_prep(const float* __restrict__ hist, const float* __restrict__ mask,
                                              const float* __restrict__ Wp, const float* __restrict__ bp,
                                              const float* __restrict__ We2, const float* __restrict__ be2,
                                              const float* __restrict__ Wa1, const float* __restrict__ ba1,
                                              const float* __restrict__ Wm1, const float* __restrict__ bm1,
                                              const float* __restrict__ Wo1, const float* __restrict__ Wm2,
                                              const float* __restrict__ Wo2,
                                              float* __restrict__ ts, float* __restrict__ h,
                                              short* __restrict__ AmT, short* __restrict__ MmT,
                                              float* __restrict__ ca, float* __restrict__ cm,
                                              short* __restrict__ WT4, short* __restrict__ WT3) {
    __shared__ float row[HH];
    const int bid = blockIdx.x, tid = threadIdx.x;
    const int NC = NLAYER * (HH + 1);
    if (bid < BB) {
        int b = bid;
        if (tid < LL) row[tid] = fmaxf(hist[(b * LL + tid) * D_IN + 5], 0.f);
        __syncthreads();
        for (int d = 1; d < LL; d <<= 1) {
            float add = (tid < LL && tid >= d) ? row[tid - d] : 0.f;
            __syncthreads();
            if (tid < LL) row[tid] += add;
            __syncthreads();
        }
        if (tid < LL) ts[b * LL + tid] = row[tid];
        int k = tid & (HH - 1);
        float wp_r[D_IN];
#pragma unroll
        for (int f = 0; f < D_IN; f++) wp_r[f] = Wp[f * HH + k];
        float bpk = bp[k];
        int jbase = tid >> 7;
        for (int e = 0; e < 64; e++) {
            int j = e * 2 + jbase;
            int bj = b * LL + j;
            const float* hr = hist + (size_t)bj * D_IN;
            float acc = bpk;
#pragma unroll
            for (int f = 0; f < D_IN; f++) acc += hr[f] * wp_r[f];
            h[(size_t)bj * HH + k] = acc * (mask[bj] > 0.f ? 1.f : 0.f);
        }
    } else if (bid < BB + NC) {
        int cb = bid - BB;
        int l = cb / (HH + 1);
        int p = cb % (HH + 1);
        const float* WaE = Wa1 + (size_t)(l * 3 * HH + 2 * HH) * HH;
        const float* WmE = Wm1 + (size_t)(l * 2 * HH + HH) * HH;
        if (tid < HH) row[tid] = (p < HH) ? We2[(size_t)(l * HH + p) * HH + tid] : be2[l * HH + tid];
        __syncthreads();
        if (tid < HH) {
            float a = 0.f, m = 0.f;
            for (int k = 0; k < HH; k++) { float w = row[k]; a += w * WaE[k * HH + tid]; m += w * WmE[k * HH + tid]; }
            if (p < HH) {
                AmT[(size_t)l * HH * HH + tid * HH + p] = f2bf(a);
                MmT[(size_t)l * HH * HH + tid * HH + p] = f2bf(m);
            } else {
                ca[l * HH + tid] = a + ba1[l * HH + tid];
                cm[l * HH + tid] = m + bm1[l * HH + tid];
            }
        }
    } else {
        int m7 = bid - BB - NC;
        int l = m7 / 7, m = m7 % 7;
        const float* src;
        switch (m) {
            case 0: src = Wa1 + (size_t)(l * 3 * HH) * HH; break;
            case 1: src = Wa1 + (size_t)(l * 3 * HH + HH) * HH; break;
            case 2: src = Wm1 + (size_t)(l * 2 * HH) * HH; break;
            case 3: src = Wo1 + (size_t)(l * 2 * HH) * HH; break;
            case 4: src = Wm2 + (size_t)l * HH * HH; break;
            case 5: src = Wo1 + (size_t)(l * 2 * HH + HH) * HH; break;
            default: src = Wo2 + (size_t)l * HH * HH; break;
        }
        short* dst = (m < 4) ? (WT4 + (size_t)(l * 4 + m) * HH * HH)
                             : (WT3 + (size_t)(l * 3 + (m - 4)) * HH * HH);
#pragma unroll 4
        for (int e = 0; e < 64; e++) {
            int idx = e * 256 + tid;
            int c = idx >> 7, kk = idx & (HH - 1);
            dst[c * HH + kk] = f2bf(src[kk * HH + c]);
        }
    }
}

// ---------------- batched pre-projections via MFMA, 16-row tiles: base_a, da, base_m, oa ----------------
__global__ __launch_bounds__(256) void k_pre(const float* __restrict__ h, const short* __restrict__ WT4,
                                             const float* __restrict__ ca, const float* __restrict__ cm,
                                             float* __restrict__ base_a, float* __restrict__ da,
                                             float* __restrict__ base_m, float* __restrict__ oa, int l) {
    __shared__ __align__(16) short hA[16][136];
    const int tid = threadIdx.x, lane = tid & 63, wv = tid >> 6;
    const int lo = lane & 15, g4 = lane >> 4;
    const int r0 = blockIdx.x * 16;
    {
        int row = tid >> 4, cc = (tid & 15) * 8;
        const float* hr = h + (size_t)(r0 + row) * HH + cc;
        short8v pk;
#pragma unroll
        for (int e = 0; e < 8; e++) pk[e] = f2bf(hr[e]);
        *(short8v*)&hA[row][cc] = pk;
    }
    __syncthreads();
    bf16x8 af[4];
#pragma unroll
    for (int ks = 0; ks < 4; ks++)
        af[ks] = *(const bf16x8*)&hA[lo][ks * 32 + g4 * 8];
    const short* Wl = WT4 + (size_t)(l * 4 + wv) * HH * HH;
    float* dst;
    const float* bias = nullptr;
    if (wv == 0) { dst = base_a; bias = ca + l * HH; }
    else if (wv == 1) dst = da;
    else if (wv == 2) { dst = base_m; bias = cm + l * HH; }
    else dst = oa;
#pragma unroll
    for (int ct = 0; ct < 8; ct++) {
        int col = ct * 16 + lo;
        bf16x8 Bf[4];
#pragma unroll
        for (int ks = 0; ks < 4; ks++)
            Bf[ks] = *(const bf16x8*)(Wl + (size_t)col * HH + ks * 32 + g4 * 8);
        f32x4 acc = (f32x4){0.f, 0.f, 0.f, 0.f};
#pragma unroll
        for (int ks = 0; ks < 4; ks++) acc = MFMA_B16(af[ks], Bf[ks], acc);
        float bv = bias ? bias[col] : 0.f;
#pragma unroll
        for (int rg = 0; rg < 4; rg++)
            dst[(size_t)(r0 + g4 * 4 + rg) * HH + col] = acc[rg] + bv;
    }
}

// ---------------- attention core: 512 threads, one block per (b,i), wave owns 16 cols ----------------
__global__ __launch_bounds__(512) void k_attn(
    const float* __restrict__ hist, const float* __restrict__ mask, const float* __restrict__ ts,
    const float* __restrict__ base_a_g, const float* __restrict__ base_m_g, const float* __restrict__ da,
    const short* __restrict__ AmT, const short* __restrict__ MmT,
    const float* __restrict__ wa2, const float* __restrict__ ba2,
    const float* __restrict__ We1, const float* __restrict__ be1,
    float* __restrict__ v_out, int l) {
    __shared__ __align__(16) short t_lds[LL][136];   // 34816 B
    __shared__ __align__(16) float bufA[1024];       // We1[0..511], be1[512..639] -> att partials [8][128]
    __shared__ float w_lds[128];
    __shared__ float val_s[128], base_a[128], base_m[128], wa2_s[128];

    const int tid = threadIdx.x;
    const int lane = tid & 63;
    const int wv = tid >> 6;            // 0..7: wave owns cols [wv*16, wv*16+16)
    const int lo = lane & 15, g4 = lane >> 4;
    const int k0 = wv * 16 + lo;
    const int bi = blockIdx.x, b = bi >> 7, i = bi & (LL - 1);

    // --- B1 fragments (Amat^T bf16), issue early (L2) ---
    bf16x8 Bf[4];
#pragma unroll
    for (int ks = 0; ks < 4; ks++)
        Bf[ks] = *(const bf16x8*)(AmT + (size_t)l * HH * HH + (size_t)k0 * HH + ks * 32 + g4 * 8);

    // --- stage ---
    bufA[tid] = We1[l * 4 * HH + tid];
    if (tid < LL) {
        val_s[tid] = mask[b * LL + tid];
        wa2_s[tid] = wa2[l * HH + tid];
        bufA[512 + tid] = be1[l * HH + tid];
        base_a[tid] = base_a_g[(size_t)bi * HH + tid];
        base_m[tid] = base_m_g[(size_t)bi * HH + tid];
    }
    __syncthreads();

    // --- per-thread edge features + t = relu(ef @ We1 + be1) -> LDS bf16 (vector LDS reads) ---
    {
        int jj = tid & (LL - 1);
        int q4 = tid >> 7;  // 0..3
        const float* hri = hist + (size_t)(b * LL + i) * D_IN;
        const float* hrj = hist + (size_t)(b * LL + jj) * D_IN;
        float dlat = hri[0] - hrj[0], dlon = hri[1] - hrj[1];
        float ea = sqrtf(dlat * dlat + dlon * dlon + 1e-8f);
        float eb = fabsf(ts[b * LL + i] - ts[b * LL + jj]) * (1.f / 300.f);
        float ec = (hri[6] == hrj[6]) ? 1.f : 0.f;
        float ed = (jj == i) ? 1.f : 0.f;
#pragma unroll
        for (int pass = 0; pass < 4; pass++) {
            int r0 = (q4 + pass * 4) * 8;
            short8v pk;
#pragma unroll
            for (int hv = 0; hv < 2; hv++) {
                f32x4 wa = *(const f32x4*)&bufA[r0 + hv * 4];
                f32x4 wb = *(const f32x4*)&bufA[128 + r0 + hv * 4];
                f32x4 wc = *(const f32x4*)&bufA[256 + r0 + hv * 4];
                f32x4 wd = *(const f32x4*)&bufA[384 + r0 + hv * 4];
                f32x4 wbe = *(const f32x4*)&bufA[512 + r0 + hv * 4];
#pragma unroll
                for (int e = 0; e < 4; e++) {
                    float v = ea * wa[e] + eb * wb[e] + ec * wc[e] + ed * wd[e] + wbe[e];
                    pk[hv * 4 + e] = f2bf(fmaxf(v, 0.f));
                }
            }
            *(short8v*)&t_lds[jj][r0] = pk;
        }
    }

    // --- acc init from da (loads hide under t-compute) ---
    f32x4 acc[8];
    const float* da_b = da + (size_t)(b * LL) * HH;
#pragma unroll
    for (int jt = 0; jt < 8; jt++)
#pragma unroll
        for (int rg = 0; rg < 4; rg++)
            acc[jt][rg] = da_b[(size_t)(jt * 16 + g4 * 4 + rg) * HH + k0];
    __syncthreads();

    // --- GEMM1: U_a = t @ Amat (this wave's 16 cols) ---
#pragma unroll
    for (int ks = 0; ks < 4; ks++) {
#pragma unroll
        for (int jh = 0; jh < 2; jh++) {
            bf16x8 tf[4];
#pragma unroll
            for (int m = 0; m < 4; m++)
                tf[m] = *(const bf16x8*)&t_lds[(jh * 4 + m) * 16 + lo][ks * 32 + g4 * 8];
#pragma unroll
            for (int m = 0; m < 4; m++)
                acc[jh * 4 + m] = MFMA_B16(tf[m], Bf[ks], acc[jh * 4 + m]);
        }
    }

    // --- preload B2 (Mmat^T) ---
#pragma unroll
    for (int ks = 0; ks < 4; ks++)
        Bf[ks] = *(const bf16x8*)(MmT + (size_t)l * HH * HH + (size_t)k0 * HH + ks * 32 + g4 * 8);

    // --- tanh + att partials (sum over this wave's 16 cols) -> bufA[wv*128 + j] ---
    {
        float ba0 = base_a[k0];
        float w0a = wa2_s[k0];
#pragma unroll
        for (int jt = 0; jt < 8; jt++) {
#pragma unroll
            for (int rg = 0; rg < 4; rg++) {
                float p = tanh_fast(acc[jt][rg] + ba0) * w0a;
                p += __shfl_xor(p, 1);
                p += __shfl_xor(p, 2);
                p += __shfl_xor(p, 4);
                p += __shfl_xor(p, 8);
                if (lo == 0) bufA[wv * LL + jt * 16 + g4 * 4 + rg] = p;
            }
        }
    }
    __syncthreads();

    // --- redundant per-wave softmax (each lane handles j=lane, j=lane+64) ---
    {
        const float inv = 0.08838834764831845f;  // 1/sqrt(128)
        float ba2l = ba2[l];
        float vi = val_s[i];
        float a0 = ba2l, a1 = ba2l;
#pragma unroll
        for (int w = 0; w < 8; w++) {
            a0 += bufA[w * LL + lane];
            a1 += bufA[w * LL + 64 + lane];
        }
        a0 *= inv; a1 *= inv;
        if (!(val_s[lane] > 0.f) || !(vi > 0.f)) a0 = -1e9f;
        if (!(val_s[64 + lane] > 0.f) || !(vi > 0.f)) a1 = -1e9f;
        float m = fmaxf(a0, a1);
#pragma unroll
        for (int d = 1; d < 64; d <<= 1) m = fmaxf(m, __shfl_xor(m, d));
        float e0 = __expf(a0 - m), e1 = __expf(a1 - m);
        float s = e0 + e1;
#pragma unroll
        for (int d = 1; d < 64; d <<= 1) s += __shfl_xor(s, d);
        float rs = 1.f / s;
        // identical values from every wave -> benign same-value race
        w_lds[lane] = e0 * rs;
        w_lds[64 + lane] = e1 * rs;
    }

    // --- GEMM2: U_m = t @ Mmat ---
#pragma unroll
    for (int jt = 0; jt < 8; jt++)
#pragma unroll
        for (int rg = 0; rg < 4; rg++) acc[jt][rg] = 0.f;
#pragma unroll
    for (int ks = 0; ks < 4; ks++) {
#pragma unroll
        for (int jh = 0; jh < 2; jh++) {
            bf16x8 tf[4];
#pragma unroll
            for (int m = 0; m < 4; m++)
                tf[m] = *(const bf16x8*)&t_lds[(jh * 4 + m) * 16 + lo][ks * 32 + g4 * 8];
#pragma unroll
            for (int m = 0; m < 4; m++)
                acc[jh * 4 + m] = MFMA_B16(tf[m], Bf[ks], acc[jh * 4 + m]);
        }
    }

    // --- weighted relu-msg sum over j (w via vector LDS reads); write v directly ---
    {
        float bm0 = base_m[k0];
        float mac = 0.f;
#pragma unroll
        for (int jt = 0; jt < 8; jt++) {
            f32x4 wj4 = *(const f32x4*)&w_lds[jt * 16 + g4 * 4];
#pragma unroll
            for (int rg = 0; rg < 4; rg++)
                mac += wj4[rg] * fmaxf(acc[jt][rg] + bm0, 0.f);
        }
        mac += __shfl_xor(mac, 16);
        mac += __shfl_xor(mac, 32);
        if (g4 == 0) v_out[(size_t)bi * HH + k0] = mac;
    }
}

// ---------------- batched post, 16-row tiles: agg -> x1 -> y, LayerNorm; optional fused next-layer pre ----------------
__global__ __launch_bounds__(256) void k_post(
    const float* __restrict__ v, const float* __restrict__ oa_in, const float* __restrict__ h,
    const float* __restrict__ mask, const short* __restrict__ WT3,
    const float* __restrict__ bm2, const float* __restrict__ bo1, const float* __restrict__ bo2,
    const float* __restrict__ ln_g, const float* __restrict__ ln_b,
    float* __restrict__ hout, float* __restrict__ hcopy, int l,
    int do_pre, const short* __restrict__ WT4, const float* __restrict__ ca, const float* __restrict__ cm,
    float* __restrict__ base_a, float* __restrict__ da, float* __restrict__ base_m, float* __restrict__ oa_out) {
    __shared__ __align__(16) short xA[16][136];
    __shared__ __align__(16) short iA[16][136];
    __shared__ float red[2][4][16];
    const int tid = threadIdx.x, lane = tid & 63, wv = tid >> 6;
    const int lo = lane & 15, g4 = lane >> 4;
    const int r0 = blockIdx.x * 16;

    float oaR[2][4], hR[2][4], vmR[4];
    float bm2R[2], bo1R[2], bo2R[2], gR[2], bR[2];
#pragma unroll
    for (int ct = 0; ct < 2; ct++) {
        int c = wv * 32 + ct * 16 + lo;
        bm2R[ct] = bm2[l * HH + c];
        bo1R[ct] = bo1[l * HH + c];
        bo2R[ct] = bo2[l * HH + c];
        gR[ct] = ln_g[l * HH + c];
        bR[ct] = ln_b[l * HH + c];
    }
#pragma unroll
    for (int rg = 0; rg < 4; rg++) {
        int r = r0 + g4 * 4 + rg;
        vmR[rg] = mask[r];
#pragma unroll
        for (int ct = 0; ct < 2; ct++) {
            int c = wv * 32 + ct * 16 + lo;
            oaR[ct][rg] = oa_in[(size_t)r * HH + c];
            hR[ct][rg] = h[(size_t)r * HH + c];
        }
    }

    {
        int row = tid >> 4, cc = (tid & 15) * 8;
        const float* vr = v + (size_t)(r0 + row) * HH + cc;
        short8v pk;
#pragma unroll
        for (int e = 0; e < 8; e++) pk[e] = f2bf(vr[e]);
        *(short8v*)&xA[row][cc] = pk;
    }
    __syncthreads();

    bf16x8 af[4], Bf[2][4];
    f32x4 acc[2];

    // ---- GEMM A: agg = v @ Wm2^T + bm2 -> iA ----
    {
        const short* W = WT3 + (size_t)(l * 3 + 0) * HH * HH;
#pragma unroll
        for (int ks = 0; ks < 4; ks++) af[ks] = *(const bf16x8*)&xA[lo][ks * 32 + g4 * 8];
#pragma unroll
        for (int ct = 0; ct < 2; ct++) {
            int col = wv * 32 + ct * 16 + lo;
#pragma unroll
            for (int ks = 0; ks < 4; ks++)
                Bf[ct][ks] = *(const bf16x8*)(W + (size_t)col * HH + ks * 32 + g4 * 8);
        }
        acc[0] = (f32x4){0.f, 0.f, 0.f, 0.f};
        acc[1] = (f32x4){0.f, 0.f, 0.f, 0.f};
#pragma unroll
        for (int ks = 0; ks < 4; ks++) {
            acc[0] = MFMA_B16(af[ks], Bf[0][ks], acc[0]);
            acc[1] = MFMA_B16(af[ks], Bf[1][ks], acc[1]);
        }
#pragma unroll
        for (int ct = 0; ct < 2; ct++)
#pragma unroll
            for (int rg = 0; rg < 4; rg++)
                iA[g4 * 4 + rg][wv * 32 + ct * 16 + lo] = f2bf(acc[ct][rg] + bm2R[ct]);
    }
    __syncthreads();

    // ---- GEMM B: x1 = relu(agg @ Wo1H^T + oa + bo1) -> xA ----
    {
        const short* W = WT3 + (size_t)(l * 3 + 1) * HH * HH;
#pragma unroll
        for (int ks = 0; ks < 4; ks++) af[ks] = *(const bf16x8*)&iA[lo][ks * 32 + g4 * 8];
#pragma unroll
        for (int ct = 0; ct < 2; ct++) {
            int col = wv * 32 + ct * 16 + lo;
#pragma unroll
            for (int ks = 0; ks < 4; ks++)
                Bf[ct][ks] = *(const bf16x8*)(W + (size_t)col * HH + ks * 32 + g4 * 8);
        }
        acc[0] = (f32x4){0.f, 0.f, 0.f, 0.f};
        acc[1] = (f32x4){0.f, 0.f, 0.f, 0.f};
#pragma unroll
        for (int ks = 0; ks < 4; ks++) {
            acc[0] = MFMA_B16(af[ks], Bf[0][ks], acc[0]);
            acc[1] = MFMA_B16(af[ks], Bf[1][ks], acc[1]);
        }
        __syncthreads();
#pragma unroll
        for (int ct = 0; ct < 2; ct++)
#pragma unroll
            for (int rg = 0; rg < 4; rg++)
                xA[g4 * 4 + rg][wv * 32 + ct * 16 + lo] =
                    f2bf(fmaxf(acc[ct][rg] + oaR[ct][rg] + bo1R[ct], 0.f));
    }
    __syncthreads();

    // ---- GEMM C: y = x1 @ Wo2^T + bo2 + h; LayerNorm ----
    float y[2][4];
    {
        const short* W = WT3 + (size_t)(l * 3 + 2) * HH * HH;
#pragma unroll
        for (int ks = 0; ks < 4; ks++) af[ks] = *(const bf16x8*)&xA[lo][ks * 32 + g4 * 8];
#pragma unroll
        for (int ct = 0; ct < 2; ct++) {
            int col = wv * 32 + ct * 16 + lo;
#pragma unroll
            for (int ks = 0; ks < 4; ks++)
                Bf[ct][ks] = *(const bf16x8*)(W + (size_t)col * HH + ks * 32 + g4 * 8);
        }
        acc[0] = (f32x4){0.f, 0.f, 0.f, 0.f};
        acc[1] = (f32x4){0.f, 0.f, 0.f, 0.f};
#pragma unroll
        for (int ks = 0; ks < 4; ks++) {
            acc[0] = MFMA_B16(af[ks], Bf[0][ks], acc[0]);
            acc[1] = MFMA_B16(af[ks], Bf[1][ks], acc[1]);
        }
#pragma unroll
        for (int ct = 0; ct < 2; ct++)
#pragma unroll
            for (int rg = 0; rg < 4; rg++)
                y[ct][rg] = acc[ct][rg] + bo2R[ct] + hR[ct][rg];
    }
#pragma unroll
    for (int rg = 0; rg < 4; rg++) {
        float s = y[0][rg] + y[1][rg];
        float s2 = y[0][rg] * y[0][rg] + y[1][rg] * y[1][rg];
#pragma unroll
        for (int d = 1; d < 16; d <<= 1) { s += __shfl_xor(s, d); s2 += __shfl_xor(s2, d); }
        if (lo == 0) {
            red[0][wv][g4 * 4 + rg] = s;
            red[1][wv][g4 * 4 + rg] = s2;
        }
    }
    __syncthreads();
#pragma unroll
    for (int rg = 0; rg < 4; rg++) {
        int rl = g4 * 4 + rg;
        float mu = (red[0][0][rl] + red[0][1][rl] + red[0][2][rl] + red[0][3][rl]) * (1.f / HH);
        float ex2 = (red[1][0][rl] + red[1][1][rl] + red[1][2][rl] + red[1][3][rl]) * (1.f / HH);
        float var = ex2 - mu * mu;
        float rs = rsqrtf(var + 1e-5f);
        float vm = vmR[rg] > 0.f ? 1.f : 0.f;
        int r = r0 + rl;
#pragma unroll
        for (int ct = 0; ct < 2; ct++) {
            int c = wv * 32 + ct * 16 + lo;
            float hv = ((y[ct][rg] - mu) * rs * gR[ct] + bR[ct]) * vm;
            hout[(size_t)r * HH + c] = hv;
            if (hcopy) hcopy[(size_t)r * HH + c] = hv;
            if (do_pre) xA[rl][c] = f2bf(hv);
        }
    }

    if (do_pre) {
        __syncthreads();
        bf16x8 af2[4];
#pragma unroll
        for (int ks = 0; ks < 4; ks++) af2[ks] = *(const bf16x8*)&xA[lo][ks * 32 + g4 * 8];
        int ln = l + 1;
        const short* Wl = WT4 + (size_t)(ln * 4 + wv) * HH * HH;
        float* dst;
        const float* bias = nullptr;
        if (wv == 0) { dst = base_a; bias = ca + ln * HH; }
        else if (wv == 1) dst = da;
        else if (wv == 2) { dst = base_m; bias = cm + ln * HH; }
        else dst = oa_out;
#pragma unroll
        for (int ct = 0; ct < 8; ct++) {
            int col = ct * 16 + lo;
            bf16x8 Bf2[4];
#pragma unroll
            for (int ks = 0; ks < 4; ks++)
                Bf2[ks] = *(const bf16x8*)(Wl + (size_t)col * HH + ks * 32 + g4 * 8);
            f32x4 a2 = (f32x4){0.f, 0.f, 0.f, 0.f};
#pragma unroll
            for (int ks = 0; ks < 4; ks++) a2 = MFMA_B16(af2[ks], Bf2[ks], a2);
            float bv = bias ? bias[col] : 0.f;
#pragma unroll
            for (int rg = 0; rg < 4; rg++)
                dst[(size_t)(r0 + g4 * 4 + rg) * HH + col] = a2[rg] + bv;
        }
    }
}

// ---------------- decoder ----------------
__global__ __launch_bounds__(HH) void k_dec(const float* __restrict__ hist, const float* __restrict__ mask,
                                            const float* __restrict__ h, const float* __restrict__ hg,
                                            const float* __restrict__ hb, const float* __restrict__ Wh1,
                                            const float* __restrict__ bh1, const float* __restrict__ Wh2,
                                            const float* __restrict__ bh2, float* __restrict__ out) {
    int b = blockIdx.x, t = threadIdx.x;
    const int N = D_IN + HH;  // 136
    __shared__ float red[HH], x_s[D_IN + HH], u_s[HH];
    red[t] = mask[b * LL + t];
    __syncthreads();
    for (int s = 64; s > 0; s >>= 1) { if (t < s) red[t] += red[t + s]; __syncthreads(); }
    int vc = (int)red[0];
    vc = min(max(vc, 1), LL);
    int last = vc - 1;
    __syncthreads();
    if (t < D_IN) x_s[t] = hist[(size_t)(b * LL + last) * D_IN + t];
    x_s[D_IN + t] = h[(size_t)(b * LL + last) * HH + t];
    __syncthreads();
    float ps = 0.f;
    for (int f = t; f < N; f += HH) ps += x_s[f];
    red[t] = ps;
    __syncthreads();
    for (int s = 64; s > 0; s >>= 1) { if (t < s) red[t] += red[t + s]; __syncthreads(); }
    float mu = red[0] / N;
    __syncthreads();
    ps = 0.f;
    for (int f = t; f < N; f += HH) { float d = x_s[f] - mu; ps += d * d; }
    red[t] = ps;
    __syncthreads();
    for (int s = 64; s > 0; s >>= 1) { if (t < s) red[t] += red[t + s]; __syncthreads(); }
    float var = red[0] / N;
    float rs = rsqrtf(var + 1e-5f);
    __syncthreads();
    for (int f = t; f < N; f += HH) x_s[f] = (x_s[f] - mu) * rs * hg[f] + hb[f];
    __syncthreads();
    float acc = bh1[t];
    for (int f = 0; f < N; f++) acc += x_s[f] * Wh1[f * HH + t];
    u_s[t] = fmaxf(acc, 0.f);
    __syncthreads();
    if (t < FUT * MDIM) {
        float o = bh2[t];
        for (int k = 0; k < HH; k++) o += u_s[k] * Wh2[k * FUT * MDIM + t];
        if (isnan(o)) o = 0.f;
        else if (isinf(o)) o = (o > 0.f) ? 1e4f : -1e4f;
        out[b * FUT * MDIM + t] = o;
    }
}

extern "C" void kernel_launch(void* const* d_in, const int* in_sizes, int n_in,
                              void* d_out, int out_size, void* d_ws, size_t ws_size,
                              hipStream_t stream) {
    const float* hist = (const float*)d_in[0];
    const float* mask = (const float*)d_in[1];
    const float* Wp  = (const float*)d_in[2];
    const float* bp  = (const float*)d_in[3];
    const float* We1 = (const float*)d_in[4];
    const float* be1 = (const float*)d_in[5];
    const float* We2 = (const float*)d_in[6];
    const float* be2 = (const float*)d_in[7];
    const float* Wa1 = (const float*)d_in[8];
    const float* ba1 = (const float*)d_in[9];
    const float* wa2 = (const float*)d_in[10];
    const float* ba2 = (const float*)d_in[11];
    const float* Wm1 = (const float*)d_in[12];
    const float* bm1 = (const float*)d_in[13];
    const float* Wm2 = (const float*)d_in[14];
    const float* bm2 = (const float*)d_in[15];
    const float* Wo1 = (const float*)d_in[16];
    const float* bo1 = (const float*)d_in[17];
    const float* Wo2 = (const float*)d_in[18];
    const float* bo2 = (const float*)d_in[19];
    const float* ln_g = (const float*)d_in[20];
    const float* ln_b = (const float*)d_in[21];
    const float* hg  = (const float*)d_in[22];
    const float* hb  = (const float*)d_in[23];
    const float* Wh1 = (const float*)d_in[24];
    const float* bh1 = (const float*)d_in[25];
    const float* Wh2 = (const float*)d_in[26];
    const float* bh2 = (const float*)d_in[27];
    float* out = (float*)d_out;

    float* ws = (float*)d_ws;
    float* ts_w   = ws; ws += BB * LL;
    float* h_w    = ws; ws += BB * LL * HH;
    float* da_w   = ws; ws += BB * LL * HH;
    float* ba_w   = ws; ws += BB * LL * HH;   // base_a
    float* bm_w   = ws; ws += BB * LL * HH;   // base_m
    float* oa_w   = ws; ws += BB * LL * HH;
    float* v_w    = ws; ws += BB * LL * HH;
    float* ca_w   = ws; ws += NLAYER * HH;
    float* cm_w   = ws; ws += NLAYER * HH;
    short* AmT_w  = (short*)ws; ws += NLAYER * HH * HH / 2;
    short* MmT_w  = (short*)ws; ws += NLAYER * HH * HH / 2;
    short* WT4_w  = (short*)ws; ws += NLAYER * 4 * HH * HH / 2;
    short* WT3_w  = (short*)ws; ws += NLAYER * 3 * HH * HH / 2;

    const int NPREP = BB + NLAYER * (HH + 1) + NLAYER * 7;
    k_prep<<<NPREP, 256, 0, stream>>>(hist, mask, Wp, bp, We2, be2, Wa1, ba1, Wm1, bm1,
                                      Wo1, Wm2, Wo2, ts_w, h_w, AmT_w, MmT_w, ca_w, cm_w, WT4_w, WT3_w);
    k_pre<<<BB * LL / 16, 256, 0, stream>>>(h_w, WT4_w, ca_w, cm_w, ba_w, da_w, bm_w, oa_w, 0);
    for (int l = 0; l < NLAYER; l++) {
        k_attn<<<BB * LL, 512, 0, stream>>>(hist, mask, ts_w, ba_w, bm_w, da_w, AmT_w, MmT_w,
                                            wa2, ba2, We1, be1, v_w, l);
        int do_pre = (l < NLAYER - 1) ? 1 : 0;
        float* hcopy = (l == NLAYER - 1) ? (out + BB * FUT * MDIM) : nullptr;
        k_post<<<BB * LL / 16, 256, 0, stream>>>(v_w, oa_w, h_w, mask, WT3_w, bm2, bo1, bo2,
                                                 ln_g, ln_b, h_w, hcopy, l,
                                                 do_pre, WT4_w, ca_w, cm_w, ba_w, da_w, bm_w, oa_w);
    }
    k_dec<<<BB, HH, 0, stream>>>(hist, mask, h_w, hg, hb, Wh1, bh1, Wh2, bh2, out);
}

// Round 8
// 268.362 us; speedup vs baseline: 1.1706x; 1.0571x over previous
//
#include <hip/hip_runtime.h>
#include <math.h>

#define BB 16
#define LL 128
#define D_IN 8
#define HH 128
#define NLAYER 2
#define FUT 12
#define MDIM 2

typedef __attribute__((ext_vector_type(8))) __bf16 bf16x8;
typedef __attribute__((ext_vector_type(8))) short short8v;
typedef __attribute__((ext_vector_type(4))) float f32x4;

#define MFMA_B16(A, B, C) __builtin_amdgcn_mfma_f32_16x16x32_bf16(A, B, C, 0, 0, 0)

static __device__ __forceinline__ short f2bf(float f) {
    union { float f; unsigned u; } v; v.f = f;
    unsigned r = v.u + 0x7FFFu + ((v.u >> 16) & 1u);
    return (short)(r >> 16);
}

static __device__ __forceinline__ float tanh_fast(float x) {
    float e = __expf(2.f * x);
    return 1.f - 2.f / (e + 1.f);
}

// ---------------- merged prep: ts+h0 | compose (split-K) | weight transpose ----------------
__global__ __launch_bounds__(256) void k_prep(const float* __restrict__ hist, const float* __restrict__ mask,
                                              const float* __restrict__ Wp, const float* __restrict__ bp,
                                              const float* __restrict__ We2, const float* __restrict__ be2,
                                              const float* __restrict__ Wa1, const float* __restrict__ ba1,
                                              const float* __restrict__ Wm1, const float* __restrict__ bm1,
                                              const float* __restrict__ Wo1, const float* __restrict__ Wm2,
                                              const float* __restrict__ Wo2,
                                              float* __restrict__ ts, float* __restrict__ h,
                                              short* __restrict__ AmT, short* __restrict__ MmT,
                                              float* __restrict__ ca, float* __restrict__ cm,
                                              short* __restrict__ WT4, short* __restrict__ WT3) {
    __shared__ float row[HH];
    __shared__ float pa[256], pm[256];
    const int bid = blockIdx.x, tid = threadIdx.x;
    const int NC = NLAYER * (HH + 1);
    if (bid < BB) {
        int b = bid;
        if (tid < LL) row[tid] = fmaxf(hist[(b * LL + tid) * D_IN + 5], 0.f);
        __syncthreads();
        for (int d = 1; d < LL; d <<= 1) {
            float add = (tid < LL && tid >= d) ? row[tid - d] : 0.f;
            __syncthreads();
            if (tid < LL) row[tid] += add;
            __syncthreads();
        }
        if (tid < LL) ts[b * LL + tid] = row[tid];
        int k = tid & (HH - 1);
        float wp_r[D_IN];
#pragma unroll
        for (int f = 0; f < D_IN; f++) wp_r[f] = Wp[f * HH + k];
        float bpk = bp[k];
        int jbase = tid >> 7;
        for (int e = 0; e < 64; e++) {
            int j = e * 2 + jbase;
            int bj = b * LL + j;
            const float* hr = hist + (size_t)bj * D_IN;
            float acc = bpk;
#pragma unroll
            for (int f = 0; f < D_IN; f++) acc += hr[f] * wp_r[f];
            h[(size_t)bj * HH + k] = acc * (mask[bj] > 0.f ? 1.f : 0.f);
        }
    } else if (bid < BB + NC) {
        int cb = bid - BB;
        int l = cb / (HH + 1);
        int p = cb % (HH + 1);
        const float* WaE = Wa1 + (size_t)(l * 3 * HH + 2 * HH) * HH;
        const float* WmE = Wm1 + (size_t)(l * 2 * HH + HH) * HH;
        int q = tid & 127, kh = tid >> 7;
        if (tid < HH) row[tid] = (p < HH) ? We2[(size_t)(l * HH + p) * HH + tid] : be2[l * HH + tid];
        __syncthreads();
        float a = 0.f, m = 0.f;
        int kbase = kh * 64;
        for (int k = 0; k < 64; k++) {
            float w = row[kbase + k];
            a += w * WaE[(size_t)(kbase + k) * HH + q];
            m += w * WmE[(size_t)(kbase + k) * HH + q];
        }
        pa[tid] = a;
        pm[tid] = m;
        __syncthreads();
        if (tid < HH) {
            a = pa[tid] + pa[128 + tid];
            m = pm[tid] + pm[128 + tid];
            if (p < HH) {
                AmT[(size_t)l * HH * HH + tid * HH + p] = f2bf(a);
                MmT[(size_t)l * HH * HH + tid * HH + p] = f2bf(m);
            } else {
                ca[l * HH + tid] = a + ba1[l * HH + tid];
                cm[l * HH + tid] = m + bm1[l * HH + tid];
            }
        }
    } else {
        int m7 = bid - BB - NC;
        int l = m7 / 7, m = m7 % 7;
        const float* src;
        switch (m) {
            case 0: src = Wa1 + (size_t)(l * 3 * HH) * HH; break;
            case 1: src = Wa1 + (size_t)(l * 3 * HH + HH) * HH; break;
            case 2: src = Wm1 + (size_t)(l * 2 * HH) * HH; break;
            case 3: src = Wo1 + (size_t)(l * 2 * HH) * HH; break;
            case 4: src = Wm2 + (size_t)l * HH * HH; break;
            case 5: src = Wo1 + (size_t)(l * 2 * HH + HH) * HH; break;
            default: src = Wo2 + (size_t)l * HH * HH; break;
        }
        short* dst = (m < 4) ? (WT4 + (size_t)(l * 4 + m) * HH * HH)
                             : (WT3 + (size_t)(l * 3 + (m - 4)) * HH * HH);
#pragma unroll 4
        for (int e = 0; e < 64; e++) {
            int idx = e * 256 + tid;
            int c = idx >> 7, kk = idx & (HH - 1);
            dst[c * HH + kk] = f2bf(src[kk * HH + c]);
        }
    }
}

// ---------------- batched pre-projections, 256 blocks: base_a, da, base_m, oa ----------------
__global__ __launch_bounds__(256) void k_pre(const float* __restrict__ h, const short* __restrict__ WT4,
                                             const float* __restrict__ ca, const float* __restrict__ cm,
                                             float* __restrict__ base_a, float* __restrict__ da,
                                             float* __restrict__ base_m, float* __restrict__ oa, int l) {
    __shared__ __align__(16) short hA[16][136];
    const int tid = threadIdx.x, lane = tid & 63, wv = tid >> 6;
    const int lo = lane & 15, g4 = lane >> 4;
    const int rt = blockIdx.x >> 1, half = blockIdx.x & 1;
    const int r0 = rt * 16;
    {
        int row = tid >> 4, cc = (tid & 15) * 8;
        const float* hr = h + (size_t)(r0 + row) * HH + cc;
        short8v pk;
#pragma unroll
        for (int e = 0; e < 8; e++) pk[e] = f2bf(hr[e]);
        *(short8v*)&hA[row][cc] = pk;
    }
    __syncthreads();
    bf16x8 af[4];
#pragma unroll
    for (int ks = 0; ks < 4; ks++)
        af[ks] = *(const bf16x8*)&hA[lo][ks * 32 + g4 * 8];
    const int mat = half * 2 + (wv & 1);
    const int ctbase = (wv >> 1) * 4;
    const short* Wl = WT4 + (size_t)(l * 4 + mat) * HH * HH;
    float* dst;
    const float* bias = nullptr;
    if (mat == 0) { dst = base_a; bias = ca + l * HH; }
    else if (mat == 1) dst = da;
    else if (mat == 2) { dst = base_m; bias = cm + l * HH; }
    else dst = oa;
#pragma unroll
    for (int cc2 = 0; cc2 < 4; cc2++) {
        int col = (ctbase + cc2) * 16 + lo;
        bf16x8 Bf[4];
#pragma unroll
        for (int ks = 0; ks < 4; ks++)
            Bf[ks] = *(const bf16x8*)(Wl + (size_t)col * HH + ks * 32 + g4 * 8);
        f32x4 acc = (f32x4){0.f, 0.f, 0.f, 0.f};
#pragma unroll
        for (int ks = 0; ks < 4; ks++) acc = MFMA_B16(af[ks], Bf[ks], acc);
        float bv = bias ? bias[col] : 0.f;
#pragma unroll
        for (int rg = 0; rg < 4; rg++)
            dst[(size_t)(r0 + g4 * 4 + rg) * HH + col] = acc[rg] + bv;
    }
}

// ---------------- attention core: 512 threads, swizzled t_lds, acc[4] halves ----------------
__global__ __launch_bounds__(512) void k_attn(
    const float* __restrict__ hist, const float* __restrict__ mask, const float* __restrict__ ts,
    const float* __restrict__ base_a_g, const float* __restrict__ base_m_g, const float* __restrict__ da,
    const short* __restrict__ AmT, const short* __restrict__ MmT,
    const float* __restrict__ wa2, const float* __restrict__ ba2,
    const float* __restrict__ We1, const float* __restrict__ be1,
    float* __restrict__ v_out, int l) {
    __shared__ __align__(16) short t_lds[LL][LL];    // 32768 B, XOR-swizzled
    __shared__ __align__(16) float bufA[1024];       // We1[0..511], be1[512..639] -> att partials [8][128]
    __shared__ float w_lds[LL];
    __shared__ float val_s[LL];                      // total 37888 B -> 4 blocks/CU

    const int tid = threadIdx.x;
    const int lane = tid & 63;
    const int wv = tid >> 6;            // 0..7: wave owns cols [wv*16, wv*16+16)
    const int lo = lane & 15, g4 = lane >> 4;
    const int k0 = wv * 16 + lo;
    const int bi = blockIdx.x, b = bi >> 7, i = bi & (LL - 1);

    // per-thread scalars (replace LDS staging of base_a/base_m/wa2)
    const float base_a_r = base_a_g[(size_t)bi * HH + k0];
    const float base_m_r = base_m_g[(size_t)bi * HH + k0];
    const float wa2_r = wa2[l * HH + k0];
    const float ba2l = ba2[l];

    // B1 fragments (Amat^T bf16), issue early
    bf16x8 Bf[4];
#pragma unroll
    for (int ks = 0; ks < 4; ks++)
        Bf[ks] = *(const bf16x8*)(AmT + (size_t)l * HH * HH + (size_t)k0 * HH + ks * 32 + g4 * 8);

    bufA[tid] = We1[l * 4 * HH + tid];
    if (tid < LL) {
        val_s[tid] = mask[b * LL + tid];
        bufA[512 + tid] = be1[l * HH + tid];
    }
    __syncthreads();

    // t = relu(ef @ We1 + be1) -> swizzled LDS bf16
    {
        int jj = tid & (LL - 1);
        int q4 = tid >> 7;  // 0..3
        const float* hri = hist + (size_t)(b * LL + i) * D_IN;
        const float* hrj = hist + (size_t)(b * LL + jj) * D_IN;
        float dlat = hri[0] - hrj[0], dlon = hri[1] - hrj[1];
        float ea = sqrtf(dlat * dlat + dlon * dlon + 1e-8f);
        float eb = fabsf(ts[b * LL + i] - ts[b * LL + jj]) * (1.f / 300.f);
        float ec = (hri[6] == hrj[6]) ? 1.f : 0.f;
        float ed = (jj == i) ? 1.f : 0.f;
        char* trow = (char*)t_lds + jj * 256;
        int swz = (jj & 7) << 4;
#pragma unroll
        for (int pass = 0; pass < 4; pass++) {
            int r0c = (q4 + pass * 4) * 8;
            short8v pk;
#pragma unroll
            for (int hv = 0; hv < 2; hv++) {
                f32x4 wa = *(const f32x4*)&bufA[r0c + hv * 4];
                f32x4 wb = *(const f32x4*)&bufA[128 + r0c + hv * 4];
                f32x4 wc = *(const f32x4*)&bufA[256 + r0c + hv * 4];
                f32x4 wd = *(const f32x4*)&bufA[384 + r0c + hv * 4];
                f32x4 wbe = *(const f32x4*)&bufA[512 + r0c + hv * 4];
#pragma unroll
                for (int e = 0; e < 4; e++) {
                    float v = ea * wa[e] + eb * wb[e] + ec * wc[e] + ed * wd[e] + wbe[e];
                    pk[hv * 4 + e] = f2bf(fmaxf(v, 0.f));
                }
            }
            *(short8v*)(trow + ((r0c * 2) ^ swz)) = pk;
        }
    }
    __syncthreads();

    const float* da_b = da + (size_t)(b * LL) * HH;
    const int rswz = (lo & 7) << 4;

    // --- GEMM1 + tanh partials, j in two halves (acc[4] -> 16 AGPR) ---
#pragma unroll
    for (int jh = 0; jh < 2; jh++) {
        f32x4 acc[4];
#pragma unroll
        for (int m = 0; m < 4; m++)
#pragma unroll
            for (int rg = 0; rg < 4; rg++)
                acc[m][rg] = da_b[(size_t)((jh * 4 + m) * 16 + g4 * 4 + rg) * HH + k0];
#pragma unroll
        for (int ks = 0; ks < 4; ks++) {
            bf16x8 tf[4];
#pragma unroll
            for (int m = 0; m < 4; m++) {
                int row = (jh * 4 + m) * 16 + lo;
                tf[m] = *(const bf16x8*)((const char*)t_lds + row * 256 + ((ks * 64 + g4 * 16) ^ rswz));
            }
#pragma unroll
            for (int m = 0; m < 4; m++) acc[m] = MFMA_B16(tf[m], Bf[ks], acc[m]);
        }
#pragma unroll
        for (int m = 0; m < 4; m++)
#pragma unroll
            for (int rg = 0; rg < 4; rg++) {
                float p = tanh_fast(acc[m][rg] + base_a_r) * wa2_r;
                p += __shfl_xor(p, 1);
                p += __shfl_xor(p, 2);
                p += __shfl_xor(p, 4);
                p += __shfl_xor(p, 8);
                if (lo == 0) bufA[wv * LL + (jh * 4 + m) * 16 + g4 * 4 + rg] = p;
            }
    }

    // preload B2 (Mmat^T)
#pragma unroll
    for (int ks = 0; ks < 4; ks++)
        Bf[ks] = *(const bf16x8*)(MmT + (size_t)l * HH * HH + (size_t)k0 * HH + ks * 32 + g4 * 8);
    __syncthreads();

    // --- redundant per-wave softmax -> w_lds (same values from every wave) ---
    {
        const float inv = 0.08838834764831845f;  // 1/sqrt(128)
        float vi = val_s[i];
        float a0 = ba2l, a1 = ba2l;
#pragma unroll
        for (int w = 0; w < 8; w++) {
            a0 += bufA[w * LL + lane];
            a1 += bufA[w * LL + 64 + lane];
        }
        a0 *= inv; a1 *= inv;
        if (!(val_s[lane] > 0.f) || !(vi > 0.f)) a0 = -1e9f;
        if (!(val_s[64 + lane] > 0.f) || !(vi > 0.f)) a1 = -1e9f;
        float m = fmaxf(a0, a1);
#pragma unroll
        for (int d = 1; d < 64; d <<= 1) m = fmaxf(m, __shfl_xor(m, d));
        float e0 = __expf(a0 - m), e1 = __expf(a1 - m);
        float s = e0 + e1;
#pragma unroll
        for (int d = 1; d < 64; d <<= 1) s += __shfl_xor(s, d);
        float rs = 1.f / s;
        w_lds[lane] = e0 * rs;
        w_lds[64 + lane] = e1 * rs;
    }

    // --- GEMM2 + weighted relu-msg sum, j halves ---
    float mac = 0.f;
#pragma unroll
    for (int jh = 0; jh < 2; jh++) {
        f32x4 acc[4];
#pragma unroll
        for (int m = 0; m < 4; m++) acc[m] = (f32x4){0.f, 0.f, 0.f, 0.f};
#pragma unroll
        for (int ks = 0; ks < 4; ks++) {
            bf16x8 tf[4];
#pragma unroll
            for (int m = 0; m < 4; m++) {
                int row = (jh * 4 + m) * 16 + lo;
                tf[m] = *(const bf16x8*)((const char*)t_lds + row * 256 + ((ks * 64 + g4 * 16) ^ rswz));
            }
#pragma unroll
            for (int m = 0; m < 4; m++) acc[m] = MFMA_B16(tf[m], Bf[ks], acc[m]);
        }
#pragma unroll
        for (int m = 0; m < 4; m++) {
            f32x4 wj4 = *(const f32x4*)&w_lds[(jh * 4 + m) * 16 + g4 * 4];
#pragma unroll
            for (int rg = 0; rg < 4; rg++)
                mac += wj4[rg] * fmaxf(acc[m][rg] + base_m_r, 0.f);
        }
    }
    mac += __shfl_xor(mac, 16);
    mac += __shfl_xor(mac, 32);
    if (g4 == 0) v_out[(size_t)bi * HH + k0] = mac;
}

// ---------------- batched post + optional fused pre + fused decoder (last layer) ----------------
__global__ __launch_bounds__(256) void k_post(
    const float* __restrict__ v, const float* __restrict__ oa_in, const float* __restrict__ h,
    const float* __restrict__ mask, const short* __restrict__ WT3,
    const float* __restrict__ bm2, const float* __restrict__ bo1, const float* __restrict__ bo2,
    const float* __restrict__ ln_g, const float* __restrict__ ln_b,
    float* __restrict__ hout, float* __restrict__ hcopy, int l,
    int do_pre, const short* __restrict__ WT4, const float* __restrict__ ca, const float* __restrict__ cm,
    float* __restrict__ base_a, float* __restrict__ da, float* __restrict__ base_m, float* __restrict__ oa_out,
    const float* __restrict__ hist, const float* __restrict__ hg, const float* __restrict__ hb,
    const float* __restrict__ Wh1, const float* __restrict__ bh1,
    const float* __restrict__ Wh2, const float* __restrict__ bh2, float* __restrict__ dec_out) {
    __shared__ __align__(16) short xA[16][136];
    __shared__ __align__(16) short iA[16][136];
    __shared__ float red[2][4][16];
    __shared__ float ln_row[HH];
    __shared__ float dec_x[D_IN + HH];
    const int tid = threadIdx.x, lane = tid & 63, wv = tid >> 6;
    const int lo = lane & 15, g4 = lane >> 4;
    const int r0 = blockIdx.x * 16;

    float oaR[2][4], hR[2][4], vmR[4];
    float bm2R[2], bo1R[2], bo2R[2], gR[2], bR[2];
#pragma unroll
    for (int ct = 0; ct < 2; ct++) {
        int c = wv * 32 + ct * 16 + lo;
        bm2R[ct] = bm2[l * HH + c];
        bo1R[ct] = bo1[l * HH + c];
        bo2R[ct] = bo2[l * HH + c];
        gR[ct] = ln_g[l * HH + c];
        bR[ct] = ln_b[l * HH + c];
    }
#pragma unroll
    for (int rg = 0; rg < 4; rg++) {
        int r = r0 + g4 * 4 + rg;
        vmR[rg] = mask[r];
#pragma unroll
        for (int ct = 0; ct < 2; ct++) {
            int c = wv * 32 + ct * 16 + lo;
            oaR[ct][rg] = oa_in[(size_t)r * HH + c];
            hR[ct][rg] = h[(size_t)r * HH + c];
        }
    }

    // vc reduction for fused decoder (last layer only)
    int lastRow = -1;
    if (hcopy) {
        float mv = (tid < LL) ? mask[(r0 >> 7) * LL + tid] : 0.f;
#pragma unroll
        for (int d = 1; d < 64; d <<= 1) mv += __shfl_xor(mv, d);
        if (lane == 0) red[0][wv][0] = mv;
    }

    {
        int row = tid >> 4, cc = (tid & 15) * 8;
        const float* vr = v + (size_t)(r0 + row) * HH + cc;
        short8v pk;
#pragma unroll
        for (int e = 0; e < 8; e++) pk[e] = f2bf(vr[e]);
        *(short8v*)&xA[row][cc] = pk;
    }
    __syncthreads();

    if (hcopy) {
        int vc = (int)(red[0][0][0] + red[0][1][0] + red[0][2][0] + red[0][3][0]);
        vc = min(max(vc, 1), LL);
        lastRow = (r0 & ~(LL - 1)) + vc - 1;
    }

    bf16x8 af[4], Bf[2][4];
    f32x4 acc[2];

    // ---- GEMM A: agg = v @ Wm2^T + bm2 -> iA ----
    {
        const short* W = WT3 + (size_t)(l * 3 + 0) * HH * HH;
#pragma unroll
        for (int ks = 0; ks < 4; ks++) af[ks] = *(const bf16x8*)&xA[lo][ks * 32 + g4 * 8];
#pragma unroll
        for (int ct = 0; ct < 2; ct++) {
            int col = wv * 32 + ct * 16 + lo;
#pragma unroll
            for (int ks = 0; ks < 4; ks++)
                Bf[ct][ks] = *(const bf16x8*)(W + (size_t)col * HH + ks * 32 + g4 * 8);
        }
        acc[0] = (f32x4){0.f, 0.f, 0.f, 0.f};
        acc[1] = (f32x4){0.f, 0.f, 0.f, 0.f};
#pragma unroll
        for (int ks = 0; ks < 4; ks++) {
            acc[0] = MFMA_B16(af[ks], Bf[0][ks], acc[0]);
            acc[1] = MFMA_B16(af[ks], Bf[1][ks], acc[1]);
        }
#pragma unroll
        for (int ct = 0; ct < 2; ct++)
#pragma unroll
            for (int rg = 0; rg < 4; rg++)
                iA[g4 * 4 + rg][wv * 32 + ct * 16 + lo] = f2bf(acc[ct][rg] + bm2R[ct]);
    }
    __syncthreads();

    // ---- GEMM B: x1 = relu(agg @ Wo1H^T + oa + bo1) -> xA ----
    {
        const short* W = WT3 + (size_t)(l * 3 + 1) * HH * HH;
#pragma unroll
        for (int ks = 0; ks < 4; ks++) af[ks] = *(const bf16x8*)&iA[lo][ks * 32 + g4 * 8];
#pragma unroll
        for (int ct = 0; ct < 2; ct++) {
            int col = wv * 32 + ct * 16 + lo;
#pragma unroll
            for (int ks = 0; ks < 4; ks++)
                Bf[ct][ks] = *(const bf16x8*)(W + (size_t)col * HH + ks * 32 + g4 * 8);
        }
        acc[0] = (f32x4){0.f, 0.f, 0.f, 0.f};
        acc[1] = (f32x4){0.f, 0.f, 0.f, 0.f};
#pragma unroll
        for (int ks = 0; ks < 4; ks++) {
            acc[0] = MFMA_B16(af[ks], Bf[0][ks], acc[0]);
            acc[1] = MFMA_B16(af[ks], Bf[1][ks], acc[1]);
        }
        __syncthreads();
#pragma unroll
        for (int ct = 0; ct < 2; ct++)
#pragma unroll
            for (int rg = 0; rg < 4; rg++)
                xA[g4 * 4 + rg][wv * 32 + ct * 16 + lo] =
                    f2bf(fmaxf(acc[ct][rg] + oaR[ct][rg] + bo1R[ct], 0.f));
    }
    __syncthreads();

    // ---- GEMM C: y = x1 @ Wo2^T + bo2 + h; LayerNorm ----
    float y[2][4];
    {
        const short* W = WT3 + (size_t)(l * 3 + 2) * HH * HH;
#pragma unroll
        for (int ks = 0; ks < 4; ks++) af[ks] = *(const bf16x8*)&xA[lo][ks * 32 + g4 * 8];
#pragma unroll
        for (int ct = 0; ct < 2; ct++) {
            int col = wv * 32 + ct * 16 + lo;
#pragma unroll
            for (int ks = 0; ks < 4; ks++)
                Bf[ct][ks] = *(const bf16x8*)(W + (size_t)col * HH + ks * 32 + g4 * 8);
        }
        acc[0] = (f32x4){0.f, 0.f, 0.f, 0.f};
        acc[1] = (f32x4){0.f, 0.f, 0.f, 0.f};
#pragma unroll
        for (int ks = 0; ks < 4; ks++) {
            acc[0] = MFMA_B16(af[ks], Bf[0][ks], acc[0]);
            acc[1] = MFMA_B16(af[ks], Bf[1][ks], acc[1]);
        }
#pragma unroll
        for (int ct = 0; ct < 2; ct++)
#pragma unroll
            for (int rg = 0; rg < 4; rg++)
                y[ct][rg] = acc[ct][rg] + bo2R[ct] + hR[ct][rg];
    }
#pragma unroll
    for (int rg = 0; rg < 4; rg++) {
        float s = y[0][rg] + y[1][rg];
        float s2 = y[0][rg] * y[0][rg] + y[1][rg] * y[1][rg];
#pragma unroll
        for (int d = 1; d < 16; d <<= 1) { s += __shfl_xor(s, d); s2 += __shfl_xor(s2, d); }
        if (lo == 0) {
            red[0][wv][g4 * 4 + rg] = s;
            red[1][wv][g4 * 4 + rg] = s2;
        }
    }
    __syncthreads();
#pragma unroll
    for (int rg = 0; rg < 4; rg++) {
        int rl = g4 * 4 + rg;
        float mu = (red[0][0][rl] + red[0][1][rl] + red[0][2][rl] + red[0][3][rl]) * (1.f / HH);
        float ex2 = (red[1][0][rl] + red[1][1][rl] + red[1][2][rl] + red[1][3][rl]) * (1.f / HH);
        float var = ex2 - mu * mu;
        float rs = rsqrtf(var + 1e-5f);
        float vm = vmR[rg] > 0.f ? 1.f : 0.f;
        int r = r0 + rl;
#pragma unroll
        for (int ct = 0; ct < 2; ct++) {
            int c = wv * 32 + ct * 16 + lo;
            float hv = ((y[ct][rg] - mu) * rs * gR[ct] + bR[ct]) * vm;
            hout[(size_t)r * HH + c] = hv;
            if (hcopy) hcopy[(size_t)r * HH + c] = hv;
            if (do_pre) xA[rl][c] = f2bf(hv);
            if (lastRow >= 0 && r == lastRow) ln_row[c] = hv;
        }
    }

    if (do_pre) {
        __syncthreads();
        bf16x8 af2[4];
#pragma unroll
        for (int ks = 0; ks < 4; ks++) af2[ks] = *(const bf16x8*)&xA[lo][ks * 32 + g4 * 8];
        int ln = l + 1;
        const short* Wl = WT4 + (size_t)(ln * 4 + wv) * HH * HH;
        float* dst;
        const float* bias = nullptr;
        if (wv == 0) { dst = base_a; bias = ca + ln * HH; }
        else if (wv == 1) dst = da;
        else if (wv == 2) { dst = base_m; bias = cm + ln * HH; }
        else dst = oa_out;
#pragma unroll
        for (int ct = 0; ct < 8; ct++) {
            int col = ct * 16 + lo;
            bf16x8 Bf2[4];
#pragma unroll
            for (int ks = 0; ks < 4; ks++)
                Bf2[ks] = *(const bf16x8*)(Wl + (size_t)col * HH + ks * 32 + g4 * 8);
            f32x4 a2 = (f32x4){0.f, 0.f, 0.f, 0.f};
#pragma unroll
            for (int ks = 0; ks < 4; ks++) a2 = MFMA_B16(af2[ks], Bf2[ks], a2);
            float bv = bias ? bias[col] : 0.f;
#pragma unroll
            for (int rg = 0; rg < 4; rg++)
                dst[(size_t)(r0 + g4 * 4 + rg) * HH + col] = a2[rg] + bv;
        }
    }

    // ---- fused decoder: only the block owning lastRow ----
    if (hcopy && lastRow >= r0 && lastRow < r0 + 16) {
        const int N = D_IN + HH;  // 136
        __syncthreads();
        if (tid < D_IN) dec_x[tid] = hist[(size_t)lastRow * D_IN + tid];
        if (tid < HH) dec_x[D_IN + tid] = ln_row[tid];
        __syncthreads();
        float px = (tid < N) ? dec_x[tid] : 0.f;
        float px2 = px * px;
#pragma unroll
        for (int d = 1; d < 64; d <<= 1) { px += __shfl_xor(px, d); px2 += __shfl_xor(px2, d); }
        if (lane == 0) { red[0][wv][0] = px; red[1][wv][0] = px2; }
        __syncthreads();
        float mu = (red[0][0][0] + red[0][1][0] + red[0][2][0] + red[0][3][0]) / (float)N;
        float ex2 = (red[1][0][0] + red[1][1][0] + red[1][2][0] + red[1][3][0]) / (float)N;
        float var = ex2 - mu * mu;
        float rs = rsqrtf(var + 1e-5f);
        if (tid < N) dec_x[tid] = (dec_x[tid] - mu) * rs * hg[tid] + hb[tid];
        __syncthreads();
        if (tid < HH) {
            float a = bh1[tid];
            for (int f = 0; f < N; f++) a += dec_x[f] * Wh1[(size_t)f * HH + tid];
            ln_row[tid] = fmaxf(a, 0.f);
        }
        __syncthreads();
        if (tid < FUT * MDIM) {
            float o = bh2[tid];
            for (int k = 0; k < HH; k++) o += ln_row[k] * Wh2[(size_t)k * FUT * MDIM + tid];
            if (isnan(o)) o = 0.f;
            else if (isinf(o)) o = (o > 0.f) ? 1e4f : -1e4f;
            dec_out[(r0 >> 7) * FUT * MDIM + tid] = o;
        }
    }
}

extern "C" void kernel_launch(void* const* d_in, const int* in_sizes, int n_in,
                              void* d_out, int out_size, void* d_ws, size_t ws_size,
                              hipStream_t stream) {
    const float* hist = (const float*)d_in[0];
    const float* mask = (const float*)d_in[1];
    const float* Wp  = (const float*)d_in[2];
    const float* bp  = (const float*)d_in[3];
    const float* We1 = (const float*)d_in[4];
    const float* be1 = (const float*)d_in[5];
    const float* We2 = (const float*)d_in[6];
    const float* be2 = (const float*)d_in[7];
    const float* Wa1 = (const float*)d_in[8];
    const float* ba1 = (const float*)d_in[9];
    const float* wa2 = (const float*)d_in[10];
    const float* ba2 = (const float*)d_in[11];
    const float* Wm1 = (const float*)d_in[12];
    const float* bm1 = (const float*)d_in[13];
    const float* Wm2 = (const float*)d_in[14];
    const float* bm2 = (const float*)d_in[15];
    const float* Wo1 = (const float*)d_in[16];
    const float* bo1 = (const float*)d_in[17];
    const float* Wo2 = (const float*)d_in[18];
    const float* bo2 = (const float*)d_in[19];
    const float* ln_g = (const float*)d_in[20];
    const float* ln_b = (const float*)d_in[21];
    const float* hg  = (const float*)d_in[22];
    const float* hb  = (const float*)d_in[23];
    const float* Wh1 = (const float*)d_in[24];
    const float* bh1 = (const float*)d_in[25];
    const float* Wh2 = (const float*)d_in[26];
    const float* bh2 = (const float*)d_in[27];
    float* out = (float*)d_out;

    float* ws = (float*)d_ws;
    float* ts_w   = ws; ws += BB * LL;
    float* h_w    = ws; ws += BB * LL * HH;
    float* da_w   = ws; ws += BB * LL * HH;
    float* ba_w   = ws; ws += BB * LL * HH;   // base_a
    float* bm_w   = ws; ws += BB * LL * HH;   // base_m
    float* oa_w   = ws; ws += BB * LL * HH;
    float* v_w    = ws; ws += BB * LL * HH;
    float* ca_w   = ws; ws += NLAYER * HH;
    float* cm_w   = ws; ws += NLAYER * HH;
    short* AmT_w  = (short*)ws; ws += NLAYER * HH * HH / 2;
    short* MmT_w  = (short*)ws; ws += NLAYER * HH * HH / 2;
    short* WT4_w  = (short*)ws; ws += NLAYER * 4 * HH * HH / 2;
    short* WT3_w  = (short*)ws; ws += NLAYER * 3 * HH * HH / 2;

    const int NPREP = BB + NLAYER * (HH + 1) + NLAYER * 7;
    k_prep<<<NPREP, 256, 0, stream>>>(hist, mask, Wp, bp, We2, be2, Wa1, ba1, Wm1, bm1,
                                      Wo1, Wm2, Wo2, ts_w, h_w, AmT_w, MmT_w, ca_w, cm_w, WT4_w, WT3_w);
    k_pre<<<BB * LL / 16 * 2, 256, 0, stream>>>(h_w, WT4_w, ca_w, cm_w, ba_w, da_w, bm_w, oa_w, 0);
    for (int l = 0; l < NLAYER; l++) {
        k_attn<<<BB * LL, 512, 0, stream>>>(hist, mask, ts_w, ba_w, bm_w, da_w, AmT_w, MmT_w,
                                            wa2, ba2, We1, be1, v_w, l);
        int do_pre = (l < NLAYER - 1) ? 1 : 0;
        float* hcopy = (l == NLAYER - 1) ? (out + BB * FUT * MDIM) : nullptr;
        k_post<<<BB * LL / 16, 256, 0, stream>>>(v_w, oa_w, h_w, mask, WT3_w, bm2, bo1, bo2,
                                                 ln_g, ln_b, h_w, hcopy, l,
                                                 do_pre, WT4_w, ca_w, cm_w, ba_w, da_w, bm_w, oa_w,
                                                 hist, hg, hb, Wh1, bh1, Wh2, bh2, out);
    }
}

// Round 9
// 253.355 us; speedup vs baseline: 1.2399x; 1.0592x over previous
//
#include <hip/hip_runtime.h>
#include <math.h>

#define BB 16
#define LL 128
#define D_IN 8
#define HH 128
#define NLAYER 2
#define FUT 12
#define MDIM 2

typedef __attribute__((ext_vector_type(8))) __bf16 bf16x8;
typedef __attribute__((ext_vector_type(8))) short short8v;
typedef __attribute__((ext_vector_type(4))) float f32x4;

#define MFMA_B16(A, B, C) __builtin_amdgcn_mfma_f32_16x16x32_bf16(A, B, C, 0, 0, 0)

static __device__ __forceinline__ short f2bf(float f) {
    union { float f; unsigned u; } v; v.f = f;
    unsigned r = v.u + 0x7FFFu + ((v.u >> 16) & 1u);
    return (short)(r >> 16);
}

static __device__ __forceinline__ float tanh_fast(float x) {
    float e = __expf(2.f * x);
    return 1.f - 2.f / (e + 1.f);
}

// ---------------- merged prep: ts+h0 | compose (split-K) | weight transpose ----------------
__global__ __launch_bounds__(256) void k_prep(const float* __restrict__ hist, const float* __restrict__ mask,
                                              const float* __restrict__ Wp, const float* __restrict__ bp,
                                              const float* __restrict__ We2, const float* __restrict__ be2,
                                              const float* __restrict__ Wa1, const float* __restrict__ ba1,
                                              const float* __restrict__ Wm1, const float* __restrict__ bm1,
                                              const float* __restrict__ Wo1, const float* __restrict__ Wm2,
                                              const float* __restrict__ Wo2,
                                              float* __restrict__ ts, float* __restrict__ h,
                                              short* __restrict__ AmT, short* __restrict__ MmT,
                                              float* __restrict__ ca, float* __restrict__ cm,
                                              short* __restrict__ WT4, short* __restrict__ WT3) {
    __shared__ float row[HH];
    __shared__ float pa[256], pm[256];
    const int bid = blockIdx.x, tid = threadIdx.x;
    const int NC = NLAYER * (HH + 1);
    if (bid < BB) {
        int b = bid;
        if (tid < LL) row[tid] = fmaxf(hist[(b * LL + tid) * D_IN + 5], 0.f);
        __syncthreads();
        for (int d = 1; d < LL; d <<= 1) {
            float add = (tid < LL && tid >= d) ? row[tid - d] : 0.f;
            __syncthreads();
            if (tid < LL) row[tid] += add;
            __syncthreads();
        }
        if (tid < LL) ts[b * LL + tid] = row[tid];
        int k = tid & (HH - 1);
        float wp_r[D_IN];
#pragma unroll
        for (int f = 0; f < D_IN; f++) wp_r[f] = Wp[f * HH + k];
        float bpk = bp[k];
        int jbase = tid >> 7;
        for (int e = 0; e < 64; e++) {
            int j = e * 2 + jbase;
            int bj = b * LL + j;
            const float* hr = hist + (size_t)bj * D_IN;
            float acc = bpk;
#pragma unroll
            for (int f = 0; f < D_IN; f++) acc += hr[f] * wp_r[f];
            h[(size_t)bj * HH + k] = acc * (mask[bj] > 0.f ? 1.f : 0.f);
        }
    } else if (bid < BB + NC) {
        int cb = bid - BB;
        int l = cb / (HH + 1);
        int p = cb % (HH + 1);
        const float* WaE = Wa1 + (size_t)(l * 3 * HH + 2 * HH) * HH;
        const float* WmE = Wm1 + (size_t)(l * 2 * HH + HH) * HH;
        int q = tid & 127, kh = tid >> 7;
        if (tid < HH) row[tid] = (p < HH) ? We2[(size_t)(l * HH + p) * HH + tid] : be2[l * HH + tid];
        __syncthreads();
        float a = 0.f, m = 0.f;
        int kbase = kh * 64;
#pragma unroll 4
        for (int k = 0; k < 64; k++) {
            float w = row[kbase + k];
            a += w * WaE[(size_t)(kbase + k) * HH + q];
            m += w * WmE[(size_t)(kbase + k) * HH + q];
        }
        pa[tid] = a;
        pm[tid] = m;
        __syncthreads();
        if (tid < HH) {
            a = pa[tid] + pa[128 + tid];
            m = pm[tid] + pm[128 + tid];
            if (p < HH) {
                AmT[(size_t)l * HH * HH + tid * HH + p] = f2bf(a);
                MmT[(size_t)l * HH * HH + tid * HH + p] = f2bf(m);
            } else {
                ca[l * HH + tid] = a + ba1[l * HH + tid];
                cm[l * HH + tid] = m + bm1[l * HH + tid];
            }
        }
    } else {
        int m7 = bid - BB - NC;
        int l = m7 / 7, m = m7 % 7;
        const float* src;
        switch (m) {
            case 0: src = Wa1 + (size_t)(l * 3 * HH) * HH; break;
            case 1: src = Wa1 + (size_t)(l * 3 * HH + HH) * HH; break;
            case 2: src = Wm1 + (size_t)(l * 2 * HH) * HH; break;
            case 3: src = Wo1 + (size_t)(l * 2 * HH) * HH; break;
            case 4: src = Wm2 + (size_t)l * HH * HH; break;
            case 5: src = Wo1 + (size_t)(l * 2 * HH + HH) * HH; break;
            default: src = Wo2 + (size_t)l * HH * HH; break;
        }
        short* dst = (m < 4) ? (WT4 + (size_t)(l * 4 + m) * HH * HH)
                             : (WT3 + (size_t)(l * 3 + (m - 4)) * HH * HH);
#pragma unroll 4
        for (int e = 0; e < 64; e++) {
            int idx = e * 256 + tid;
            int c = idx >> 7, kk = idx & (HH - 1);
            dst[c * HH + kk] = f2bf(src[kk * HH + c]);
        }
    }
}

// ---------------- batched pre-projections, 256 blocks: base_a, da, base_m, oa ----------------
__global__ __launch_bounds__(256) void k_pre(const float* __restrict__ h, const short* __restrict__ WT4,
                                             const float* __restrict__ ca, const float* __restrict__ cm,
                                             float* __restrict__ base_a, float* __restrict__ da,
                                             float* __restrict__ base_m, float* __restrict__ oa, int l) {
    __shared__ __align__(16) short hA[16][136];
    const int tid = threadIdx.x, lane = tid & 63, wv = tid >> 6;
    const int lo = lane & 15, g4 = lane >> 4;
    const int rt = blockIdx.x >> 1, half = blockIdx.x & 1;
    const int r0 = rt * 16;
    {
        int row = tid >> 4, cc = (tid & 15) * 8;
        const float* hr = h + (size_t)(r0 + row) * HH + cc;
        short8v pk;
#pragma unroll
        for (int e = 0; e < 8; e++) pk[e] = f2bf(hr[e]);
        *(short8v*)&hA[row][cc] = pk;
    }
    __syncthreads();
    bf16x8 af[4];
#pragma unroll
    for (int ks = 0; ks < 4; ks++)
        af[ks] = *(const bf16x8*)&hA[lo][ks * 32 + g4 * 8];
    const int mat = half * 2 + (wv & 1);
    const int ctbase = (wv >> 1) * 4;
    const short* Wl = WT4 + (size_t)(l * 4 + mat) * HH * HH;
    float* dst;
    const float* bias = nullptr;
    if (mat == 0) { dst = base_a; bias = ca + l * HH; }
    else if (mat == 1) dst = da;
    else if (mat == 2) { dst = base_m; bias = cm + l * HH; }
    else dst = oa;
#pragma unroll
    for (int cc2 = 0; cc2 < 4; cc2++) {
        int col = (ctbase + cc2) * 16 + lo;
        bf16x8 Bf[4];
#pragma unroll
        for (int ks = 0; ks < 4; ks++)
            Bf[ks] = *(const bf16x8*)(Wl + (size_t)col * HH + ks * 32 + g4 * 8);
        f32x4 acc = (f32x4){0.f, 0.f, 0.f, 0.f};
#pragma unroll
        for (int ks = 0; ks < 4; ks++) acc = MFMA_B16(af[ks], Bf[ks], acc);
        float bv = bias ? bias[col] : 0.f;
#pragma unroll
        for (int rg = 0; rg < 4; rg++)
            dst[(size_t)(r0 + g4 * 4 + rg) * HH + col] = acc[rg] + bv;
    }
}

// ---------------- attention core: 512 threads, C[k][j] orientation ----------------
__global__ __launch_bounds__(512) void k_attn(
    const float* __restrict__ hist, const float* __restrict__ mask, const float* __restrict__ ts,
    const float* __restrict__ base_a_g, const float* __restrict__ base_m_g, const float* __restrict__ da,
    const short* __restrict__ AmT, const short* __restrict__ MmT,
    const float* __restrict__ wa2, const float* __restrict__ ba2,
    const float* __restrict__ We1, const float* __restrict__ be1,
    float* __restrict__ v_out, int l) {
    __shared__ __align__(16) short t_lds[LL][LL];    // 32768 B, XOR-swizzled
    __shared__ __align__(16) float bufA[1024];       // staging -> att partials [8][128]
    __shared__ float w_lds[LL];
    __shared__ float val_s[LL];                      // total 37888 B

    const int tid = threadIdx.x;
    const int lane = tid & 63;
    const int wv = tid >> 6;            // wave owns k rows [wv*16, wv*16+16)
    const int lo = lane & 15, g4 = lane >> 4;
    const int kq = wv * 16 + g4 * 4;    // this lane's k-quad base (C rows)
    const int bi = blockIdx.x, b = bi >> 7, i = bi & (LL - 1);

    // per-lane k-quad params (broadcast f32x4 loads)
    const f32x4 ba4 = *(const f32x4*)(base_a_g + (size_t)bi * HH + kq);
    const f32x4 bm4 = *(const f32x4*)(base_m_g + (size_t)bi * HH + kq);
    const f32x4 wa4 = *(const f32x4*)(wa2 + l * HH + kq);
    const float ba2l = ba2[l];

    // A-frags from AmT (rows k = wv*16+lo) — same addresses as before
    bf16x8 Bf[4];
#pragma unroll
    for (int ks = 0; ks < 4; ks++)
        Bf[ks] = *(const bf16x8*)(AmT + (size_t)l * HH * HH + (size_t)(wv * 16 + lo) * HH + ks * 32 + g4 * 8);

    // stage: [0..127]=Wa(dist) [128..255]=Wb(dt) [256..383]=base0(be) [384..511]=base1(be+Wc) [512..639]=Wd
    {
        const float* We1l = We1 + l * 4 * HH;
        const float* be1l = be1 + l * HH;
        if (tid < 256) bufA[tid] = We1l[tid];
        else if (tid < 384) bufA[tid] = be1l[tid - 256];
        else bufA[tid] = be1l[tid - 384] + We1l[256 + (tid - 384)];
        if (tid < 128) {
            bufA[512 + tid] = We1l[384 + tid];
            val_s[tid] = mask[b * LL + tid];
        }
    }
    __syncthreads();

    // t = relu(ea*Wa + eb*Wb + base_sel (+Wd if diag)) -> swizzled LDS bf16
    {
        int jj = tid & (LL - 1);
        int q4 = tid >> 7;  // 0..3
        const float* hri = hist + (size_t)(b * LL + i) * D_IN;
        const float* hrj = hist + (size_t)(b * LL + jj) * D_IN;
        float dlat = hri[0] - hrj[0], dlon = hri[1] - hrj[1];
        float ea = sqrtf(dlat * dlat + dlon * dlon + 1e-8f);
        float eb = fabsf(ts[b * LL + i] - ts[b * LL + jj]) * (1.f / 300.f);
        const float* basep = bufA + ((hri[6] == hrj[6]) ? 384 : 256);
        char* trow = (char*)t_lds + jj * 256;
        int swz = (jj & 7) << 4;
#pragma unroll
        for (int pass = 0; pass < 4; pass++) {
            int r0c = (q4 + pass * 4) * 8;
            float vv[8];
#pragma unroll
            for (int hv = 0; hv < 2; hv++) {
                f32x4 wa = *(const f32x4*)&bufA[r0c + hv * 4];
                f32x4 wb = *(const f32x4*)&bufA[128 + r0c + hv * 4];
                f32x4 bs = *(const f32x4*)&basep[r0c + hv * 4];
#pragma unroll
                for (int e = 0; e < 4; e++)
                    vv[hv * 4 + e] = ea * wa[e] + eb * wb[e] + bs[e];
            }
            if (jj == i) {  // diagonal: add same_step weight (4 threads/block)
#pragma unroll
                for (int e = 0; e < 8; e++) vv[e] += bufA[512 + r0c + e];
            }
            short8v pk;
#pragma unroll
            for (int e = 0; e < 8; e++) pk[e] = f2bf(fmaxf(vv[e], 0.f));
            *(short8v*)(trow + ((r0c * 2) ^ swz)) = pk;
        }
    }
    __syncthreads();

    const float* da_b = da + (size_t)(b * LL) * HH;
    const int rswz = (lo & 7) << 4;

    // --- GEMM1 (C[k][j]) + tanh partials, j in two halves ---
#pragma unroll
    for (int jh = 0; jh < 2; jh++) {
        f32x4 acc[4];
#pragma unroll
        for (int m = 0; m < 4; m++) {
            int j0 = (jh * 4 + m) * 16 + lo;
            acc[m] = *(const f32x4*)(da_b + (size_t)j0 * HH + kq);
        }
#pragma unroll
        for (int ks = 0; ks < 4; ks++) {
            bf16x8 tf[4];
#pragma unroll
            for (int m = 0; m < 4; m++) {
                int row = (jh * 4 + m) * 16 + lo;
                tf[m] = *(const bf16x8*)((const char*)t_lds + row * 256 + ((ks * 64 + g4 * 16) ^ rswz));
            }
#pragma unroll
            for (int m = 0; m < 4; m++) acc[m] = MFMA_B16(Bf[ks], tf[m], acc[m]);
        }
#pragma unroll
        for (int m = 0; m < 4; m++) {
            float p0 = tanh_fast(acc[m][0] + ba4[0]) * wa4[0];
            float p1 = tanh_fast(acc[m][1] + ba4[1]) * wa4[1];
            float p2 = tanh_fast(acc[m][2] + ba4[2]) * wa4[2];
            float p3 = tanh_fast(acc[m][3] + ba4[3]) * wa4[3];
            float p = (p0 + p1) + (p2 + p3);
            p += __shfl_xor(p, 16);
            p += __shfl_xor(p, 32);
            if (g4 == 0) bufA[wv * LL + (jh * 4 + m) * 16 + lo] = p;
        }
    }

    // preload B2 (MmT)
#pragma unroll
    for (int ks = 0; ks < 4; ks++)
        Bf[ks] = *(const bf16x8*)(MmT + (size_t)l * HH * HH + (size_t)(wv * 16 + lo) * HH + ks * 32 + g4 * 8);
    __syncthreads();

    // --- redundant per-wave softmax -> w_lds ---
    {
        const float inv = 0.08838834764831845f;  // 1/sqrt(128)
        float vi = val_s[i];
        float a0 = ba2l, a1 = ba2l;
#pragma unroll
        for (int w = 0; w < 8; w++) {
            a0 += bufA[w * LL + lane];
            a1 += bufA[w * LL + 64 + lane];
        }
        a0 *= inv; a1 *= inv;
        if (!(val_s[lane] > 0.f) || !(vi > 0.f)) a0 = -1e9f;
        if (!(val_s[64 + lane] > 0.f) || !(vi > 0.f)) a1 = -1e9f;
        float m = fmaxf(a0, a1);
#pragma unroll
        for (int d = 1; d < 64; d <<= 1) m = fmaxf(m, __shfl_xor(m, d));
        float e0 = __expf(a0 - m), e1 = __expf(a1 - m);
        float s = e0 + e1;
#pragma unroll
        for (int d = 1; d < 64; d <<= 1) s += __shfl_xor(s, d);
        float rs = 1.f / s;
        w_lds[lane] = e0 * rs;
        w_lds[64 + lane] = e1 * rs;
    }

    // --- GEMM2 (C[k][j]) + weighted relu-msg sum over j ---
    f32x4 macv = (f32x4){0.f, 0.f, 0.f, 0.f};
#pragma unroll
    for (int jh = 0; jh < 2; jh++) {
        f32x4 acc[4];
#pragma unroll
        for (int m = 0; m < 4; m++) acc[m] = (f32x4){0.f, 0.f, 0.f, 0.f};
#pragma unroll
        for (int ks = 0; ks < 4; ks++) {
            bf16x8 tf[4];
#pragma unroll
            for (int m = 0; m < 4; m++) {
                int row = (jh * 4 + m) * 16 + lo;
                tf[m] = *(const bf16x8*)((const char*)t_lds + row * 256 + ((ks * 64 + g4 * 16) ^ rswz));
            }
#pragma unroll
            for (int m = 0; m < 4; m++) acc[m] = MFMA_B16(Bf[ks], tf[m], acc[m]);
        }
#pragma unroll
        for (int m = 0; m < 4; m++) {
            float wj = w_lds[(jh * 4 + m) * 16 + lo];
#pragma unroll
            for (int rg = 0; rg < 4; rg++)
                macv[rg] += wj * fmaxf(acc[m][rg] + bm4[rg], 0.f);
        }
    }
#pragma unroll
    for (int rg = 0; rg < 4; rg++) {
        macv[rg] += __shfl_xor(macv[rg], 1);
        macv[rg] += __shfl_xor(macv[rg], 2);
        macv[rg] += __shfl_xor(macv[rg], 4);
        macv[rg] += __shfl_xor(macv[rg], 8);
    }
    if (lo == 0) *(f32x4*)(v_out + (size_t)bi * HH + kq) = macv;
}

// ---------------- batched post + optional fused pre + fused decoder (last layer) ----------------
__global__ __launch_bounds__(256) void k_post(
    const float* __restrict__ v, const float* __restrict__ oa_in, const float* __restrict__ h,
    const float* __restrict__ mask, const short* __restrict__ WT3,
    const float* __restrict__ bm2, const float* __restrict__ bo1, const float* __restrict__ bo2,
    const float* __restrict__ ln_g, const float* __restrict__ ln_b,
    float* __restrict__ hout, float* __restrict__ hcopy, int l,
    int do_pre, const short* __restrict__ WT4, const float* __restrict__ ca, const float* __restrict__ cm,
    float* __restrict__ base_a, float* __restrict__ da, float* __restrict__ base_m, float* __restrict__ oa_out,
    const float* __restrict__ hist, const float* __restrict__ hg, const float* __restrict__ hb,
    const float* __restrict__ Wh1, const float* __restrict__ bh1,
    const float* __restrict__ Wh2, const float* __restrict__ bh2, float* __restrict__ dec_out) {
    __shared__ __align__(16) short xA[16][136];
    __shared__ __align__(16) short iA[16][136];
    __shared__ float red[2][4][16];
    __shared__ float ln_row[HH];
    __shared__ float dec_x[D_IN + HH];
    const int tid = threadIdx.x, lane = tid & 63, wv = tid >> 6;
    const int lo = lane & 15, g4 = lane >> 4;
    const int r0 = blockIdx.x * 16;

    float oaR[2][4], hR[2][4], vmR[4];
    float bm2R[2], bo1R[2], bo2R[2], gR[2], bR[2];
#pragma unroll
    for (int ct = 0; ct < 2; ct++) {
        int c = wv * 32 + ct * 16 + lo;
        bm2R[ct] = bm2[l * HH + c];
        bo1R[ct] = bo1[l * HH + c];
        bo2R[ct] = bo2[l * HH + c];
        gR[ct] = ln_g[l * HH + c];
        bR[ct] = ln_b[l * HH + c];
    }
#pragma unroll
    for (int rg = 0; rg < 4; rg++) {
        int r = r0 + g4 * 4 + rg;
        vmR[rg] = mask[r];
#pragma unroll
        for (int ct = 0; ct < 2; ct++) {
            int c = wv * 32 + ct * 16 + lo;
            oaR[ct][rg] = oa_in[(size_t)r * HH + c];
            hR[ct][rg] = h[(size_t)r * HH + c];
        }
    }

    int lastRow = -1;
    if (hcopy) {
        float mv = (tid < LL) ? mask[(r0 >> 7) * LL + tid] : 0.f;
#pragma unroll
        for (int d = 1; d < 64; d <<= 1) mv += __shfl_xor(mv, d);
        if (lane == 0) red[0][wv][0] = mv;
    }

    {
        int row = tid >> 4, cc = (tid & 15) * 8;
        const float* vr = v + (size_t)(r0 + row) * HH + cc;
        short8v pk;
#pragma unroll
        for (int e = 0; e < 8; e++) pk[e] = f2bf(vr[e]);
        *(short8v*)&xA[row][cc] = pk;
    }
    __syncthreads();

    if (hcopy) {
        int vc = (int)(red[0][0][0] + red[0][1][0] + red[0][2][0] + red[0][3][0]);
        vc = min(max(vc, 1), LL);
        lastRow = (r0 & ~(LL - 1)) + vc - 1;
    }

    bf16x8 af[4], Bf[2][4];
    f32x4 acc[2];

    // ---- GEMM A: agg = v @ Wm2^T + bm2 -> iA ----
    {
        const short* W = WT3 + (size_t)(l * 3 + 0) * HH * HH;
#pragma unroll
        for (int ks = 0; ks < 4; ks++) af[ks] = *(const bf16x8*)&xA[lo][ks * 32 + g4 * 8];
#pragma unroll
        for (int ct = 0; ct < 2; ct++) {
            int col = wv * 32 + ct * 16 + lo;
#pragma unroll
            for (int ks = 0; ks < 4; ks++)
                Bf[ct][ks] = *(const bf16x8*)(W + (size_t)col * HH + ks * 32 + g4 * 8);
        }
        acc[0] = (f32x4){0.f, 0.f, 0.f, 0.f};
        acc[1] = (f32x4){0.f, 0.f, 0.f, 0.f};
#pragma unroll
        for (int ks = 0; ks < 4; ks++) {
            acc[0] = MFMA_B16(af[ks], Bf[0][ks], acc[0]);
            acc[1] = MFMA_B16(af[ks], Bf[1][ks], acc[1]);
        }
#pragma unroll
        for (int ct = 0; ct < 2; ct++)
#pragma unroll
            for (int rg = 0; rg < 4; rg++)
                iA[g4 * 4 + rg][wv * 32 + ct * 16 + lo] = f2bf(acc[ct][rg] + bm2R[ct]);
    }
    __syncthreads();

    // ---- GEMM B: x1 = relu(agg @ Wo1H^T + oa + bo1) -> xA ----
    {
        const short* W = WT3 + (size_t)(l * 3 + 1) * HH * HH;
#pragma unroll
        for (int ks = 0; ks < 4; ks++) af[ks] = *(const bf16x8*)&iA[lo][ks * 32 + g4 * 8];
#pragma unroll
        for (int ct = 0; ct < 2; ct++) {
            int col = wv * 32 + ct * 16 + lo;
#pragma unroll
            for (int ks = 0; ks < 4; ks++)
                Bf[ct][ks] = *(const bf16x8*)(W + (size_t)col * HH + ks * 32 + g4 * 8);
        }
        acc[0] = (f32x4){0.f, 0.f, 0.f, 0.f};
        acc[1] = (f32x4){0.f, 0.f, 0.f, 0.f};
#pragma unroll
        for (int ks = 0; ks < 4; ks++) {
            acc[0] = MFMA_B16(af[ks], Bf[0][ks], acc[0]);
            acc[1] = MFMA_B16(af[ks], Bf[1][ks], acc[1]);
        }
        __syncthreads();
#pragma unroll
        for (int ct = 0; ct < 2; ct++)
#pragma unroll
            for (int rg = 0; rg < 4; rg++)
                xA[g4 * 4 + rg][wv * 32 + ct * 16 + lo] =
                    f2bf(fmaxf(acc[ct][rg] + oaR[ct][rg] + bo1R[ct], 0.f));
    }
    __syncthreads();

    // ---- GEMM C: y = x1 @ Wo2^T + bo2 + h; LayerNorm ----
    float y[2][4];
    {
        const short* W = WT3 + (size_t)(l * 3 + 2) * HH * HH;
#pragma unroll
        for (int ks = 0; ks < 4; ks++) af[ks] = *(const bf16x8*)&xA[lo][ks * 32 + g4 * 8];
#pragma unroll
        for (int ct = 0; ct < 2; ct++) {
            int col = wv * 32 + ct * 16 + lo;
#pragma unroll
            for (int ks = 0; ks < 4; ks++)
                Bf[ct][ks] = *(const bf16x8*)(W + (size_t)col * HH + ks * 32 + g4 * 8);
        }
        acc[0] = (f32x4){0.f, 0.f, 0.f, 0.f};
        acc[1] = (f32x4){0.f, 0.f, 0.f, 0.f};
#pragma unroll
        for (int ks = 0; ks < 4; ks++) {
            acc[0] = MFMA_B16(af[ks], Bf[0][ks], acc[0]);
            acc[1] = MFMA_B16(af[ks], Bf[1][ks], acc[1]);
        }
#pragma unroll
        for (int ct = 0; ct < 2; ct++)
#pragma unroll
            for (int rg = 0; rg < 4; rg++)
                y[ct][rg] = acc[ct][rg] + bo2R[ct] + hR[ct][rg];
    }
#pragma unroll
    for (int rg = 0; rg < 4; rg++) {
        float s = y[0][rg] + y[1][rg];
        float s2 = y[0][rg] * y[0][rg] + y[1][rg] * y[1][rg];
#pragma unroll
        for (int d = 1; d < 16; d <<= 1) { s += __shfl_xor(s, d); s2 += __shfl_xor(s2, d); }
        if (lo == 0) {
            red[0][wv][g4 * 4 + rg] = s;
            red[1][wv][g4 * 4 + rg] = s2;
        }
    }
    __syncthreads();
#pragma unroll
    for (int rg = 0; rg < 4; rg++) {
        int rl = g4 * 4 + rg;
        float mu = (red[0][0][rl] + red[0][1][rl] + red[0][2][rl] + red[0][3][rl]) * (1.f / HH);
        float ex2 = (red[1][0][rl] + red[1][1][rl] + red[1][2][rl] + red[1][3][rl]) * (1.f / HH);
        float var = ex2 - mu * mu;
        float rs = rsqrtf(var + 1e-5f);
        float vm = vmR[rg] > 0.f ? 1.f : 0.f;
        int r = r0 + rl;
#pragma unroll
        for (int ct = 0; ct < 2; ct++) {
            int c = wv * 32 + ct * 16 + lo;
            float hv = ((y[ct][rg] - mu) * rs * gR[ct] + bR[ct]) * vm;
            hout[(size_t)r * HH + c] = hv;
            if (hcopy) hcopy[(size_t)r * HH + c] = hv;
            if (do_pre) xA[rl][c] = f2bf(hv);
            if (lastRow >= 0 && r == lastRow) ln_row[c] = hv;
        }
    }

    if (do_pre) {
        __syncthreads();
        bf16x8 af2[4];
#pragma unroll
        for (int ks = 0; ks < 4; ks++) af2[ks] = *(const bf16x8*)&xA[lo][ks * 32 + g4 * 8];
        int ln = l + 1;
        const short* Wl = WT4 + (size_t)(ln * 4 + wv) * HH * HH;
        float* dst;
        const float* bias = nullptr;
        if (wv == 0) { dst = base_a; bias = ca + ln * HH; }
        else if (wv == 1) dst = da;
        else if (wv == 2) { dst = base_m; bias = cm + ln * HH; }
        else dst = oa_out;
#pragma unroll
        for (int ct = 0; ct < 8; ct++) {
            int col = ct * 16 + lo;
            bf16x8 Bf2[4];
#pragma unroll
            for (int ks = 0; ks < 4; ks++)
                Bf2[ks] = *(const bf16x8*)(Wl + (size_t)col * HH + ks * 32 + g4 * 8);
            f32x4 a2 = (f32x4){0.f, 0.f, 0.f, 0.f};
#pragma unroll
            for (int ks = 0; ks < 4; ks++) a2 = MFMA_B16(af2[ks], Bf2[ks], a2);
            float bv = bias ? bias[col] : 0.f;
#pragma unroll
            for (int rg = 0; rg < 4; rg++)
                dst[(size_t)(r0 + g4 * 4 + rg) * HH + col] = a2[rg] + bv;
        }
    }

    // ---- fused decoder: only the block owning lastRow ----
    if (hcopy && lastRow >= r0 && lastRow < r0 + 16) {
        const int N = D_IN + HH;  // 136
        __syncthreads();
        if (tid < D_IN) dec_x[tid] = hist[(size_t)lastRow * D_IN + tid];
        if (tid < HH) dec_x[D_IN + tid] = ln_row[tid];
        __syncthreads();
        float px = (tid < N) ? dec_x[tid] : 0.f;
        float px2 = px * px;
#pragma unroll
        for (int d = 1; d < 64; d <<= 1) { px += __shfl_xor(px, d); px2 += __shfl_xor(px2, d); }
        if (lane == 0) { red[0][wv][0] = px; red[1][wv][0] = px2; }
        __syncthreads();
        float mu = (red[0][0][0] + red[0][1][0] + red[0][2][0] + red[0][3][0]) / (float)N;
        float ex2 = (red[1][0][0] + red[1][1][0] + red[1][2][0] + red[1][3][0]) / (float)N;
        float var = ex2 - mu * mu;
        float rs = rsqrtf(var + 1e-5f);
        if (tid < N) dec_x[tid] = (dec_x[tid] - mu) * rs * hg[tid] + hb[tid];
        __syncthreads();
        if (tid < HH) {
            float a = bh1[tid];
            for (int f = 0; f < N; f++) a += dec_x[f] * Wh1[(size_t)f * HH + tid];
            ln_row[tid] = fmaxf(a, 0.f);
        }
        __syncthreads();
        if (tid < FUT * MDIM) {
            float o = bh2[tid];
            for (int k = 0; k < HH; k++) o += ln_row[k] * Wh2[(size_t)k * FUT * MDIM + tid];
            if (isnan(o)) o = 0.f;
            else if (isinf(o)) o = (o > 0.f) ? 1e4f : -1e4f;
            dec_out[(r0 >> 7) * FUT * MDIM + tid] = o;
        }
    }
}

extern "C" void kernel_launch(void* const* d_in, const int* in_sizes, int n_in,
                              void* d_out, int out_size, void* d_ws, size_t ws_size,
                              hipStream_t stream) {
    const float* hist = (const float*)d_in[0];
    const float* mask = (const float*)d_in[1];
    const float* Wp  = (const float*)d_in[2];
    const float* bp  = (const float*)d_in[3];
    const float* We1 = (const float*)d_in[4];
    const float* be1 = (const float*)d_in[5];
    const float* We2 = (const float*)d_in[6];
    const float* be2 = (const float*)d_in[7];
    const float* Wa1 = (const float*)d_in[8];
    const float* ba1 = (const float*)d_in[9];
    const float* wa2 = (const float*)d_in[10];
    const float* ba2 = (const float*)d_in[11];
    const float* Wm1 = (const float*)d_in[12];
    const float* bm1 = (const float*)d_in[13];
    const float* Wm2 = (const float*)d_in[14];
    const float* bm2 = (const float*)d_in[15];
    const float* Wo1 = (const float*)d_in[16];
    const float* bo1 = (const float*)d_in[17];
    const float* Wo2 = (const float*)d_in[18];
    const float* bo2 = (const float*)d_in[19];
    const float* ln_g = (const float*)d_in[20];
    const float* ln_b = (const float*)d_in[21];
    const float* hg  = (const float*)d_in[22];
    const float* hb  = (const float*)d_in[23];
    const float* Wh1 = (const float*)d_in[24];
    const float* bh1 = (const float*)d_in[25];
    const float* Wh2 = (const float*)d_in[26];
    const float* bh2 = (const float*)d_in[27];
    float* out = (float*)d_out;

    float* ws = (float*)d_ws;
    float* ts_w   = ws; ws += BB * LL;
    float* h_w    = ws; ws += BB * LL * HH;
    float* da_w   = ws; ws += BB * LL * HH;
    float* ba_w   = ws; ws += BB * LL * HH;   // base_a
    float* bm_w   = ws; ws += BB * LL * HH;   // base_m
    float* oa_w   = ws; ws += BB * LL * HH;
    float* v_w    = ws; ws += BB * LL * HH;
    float* ca_w   = ws; ws += NLAYER * HH;
    float* cm_w   = ws; ws += NLAYER * HH;
    short* AmT_w  = (short*)ws; ws += NLAYER * HH * HH / 2;
    short* MmT_w  = (short*)ws; ws += NLAYER * HH * HH / 2;
    short* WT4_w  = (short*)ws; ws += NLAYER * 4 * HH * HH / 2;
    short* WT3_w  = (short*)ws; ws += NLAYER * 3 * HH * HH / 2;

    const int NPREP = BB + NLAYER * (HH + 1) + NLAYER * 7;
    k_prep<<<NPREP, 256, 0, stream>>>(hist, mask, Wp, bp, We2, be2, Wa1, ba1, Wm1, bm1,
                                      Wo1, Wm2, Wo2, ts_w, h_w, AmT_w, MmT_w, ca_w, cm_w, WT4_w, WT3_w);
    k_pre<<<BB * LL / 16 * 2, 256, 0, stream>>>(h_w, WT4_w, ca_w, cm_w, ba_w, da_w, bm_w, oa_w, 0);
    for (int l = 0; l < NLAYER; l++) {
        k_attn<<<BB * LL, 512, 0, stream>>>(hist, mask, ts_w, ba_w, bm_w, da_w, AmT_w, MmT_w,
                                            wa2, ba2, We1, be1, v_w, l);
        int do_pre = (l < NLAYER - 1) ? 1 : 0;
        float* hcopy = (l == NLAYER - 1) ? (out + BB * FUT * MDIM) : nullptr;
        k_post<<<BB * LL / 16, 256, 0, stream>>>(v_w, oa_w, h_w, mask, WT3_w, bm2, bo1, bo2,
                                                 ln_g, ln_b, h_w, hcopy, l,
                                                 do_pre, WT4_w, ca_w, cm_w, ba_w, da_w, bm_w, oa_w,
                                                 hist, hg, hb, Wh1, bh1, Wh2, bh2, out);
    }
}